// Round 1
// baseline (291.081 us; speedup 1.0000x reference)
//
#include <hip/hip_runtime.h>

// Problem constants
#define DL 16384   // D*L tokens
#define LL 2048
#define NQB 64     // NQ
#define QBS 32     // QB
#define KBS 128    // KB

__device__ __forceinline__ float sigmoidf_(float x) { return 1.f / (1.f + expf(-x)); }

// ---------------------------------------------------------------------------
// Kernel 1: adaLN1 + QKV+G projections.  One block = 32 tokens, 256 threads.
// ---------------------------------------------------------------------------
__global__ __launch_bounds__(256) void k_adaln_qkvg(
    const float* __restrict__ A_I, const float* __restrict__ S_I,
    const float* __restrict__ Wg1, const float* __restrict__ bg1, const float* __restrict__ Ws1,
    const float* __restrict__ Wq, const float* __restrict__ bq,
    const float* __restrict__ Wk, const float* __restrict__ Wv, const float* __restrict__ Wga,
    float* __restrict__ Qo, float* __restrict__ Ko, float* __restrict__ Vo, float* __restrict__ Go)
{
    __shared__ float sa[32 * 128];   // LN(A)
    __shared__ float ss[32 * 128];   // LN(S)
    __shared__ float san[32 * 128];  // An
    const int tid = threadIdx.x;
    const long t0 = (long)blockIdx.x * 32;

    {   // cooperative vectorized load of A,S tiles
        const float4* A4 = (const float4*)(A_I + t0 * 128);
        const float4* S4 = (const float4*)(S_I + t0 * 128);
        float4* sa4 = (float4*)sa;
        float4* ss4 = (float4*)ss;
        #pragma unroll
        for (int k2 = 0; k2 < 4; ++k2) {
            sa4[tid + 256 * k2] = A4[tid + 256 * k2];
            ss4[tid + 256 * k2] = S4[tid + 256 * k2];
        }
    }
    __syncthreads();
    {   // LayerNorm rows in place: 8 lanes per row, 16 contiguous elems each
        const int r = tid >> 3;
        const int c0 = (tid & 7) * 16;
        float sm = 0.f, sq = 0.f;
        #pragma unroll
        for (int c = 0; c < 16; ++c) { float x = sa[r * 128 + c0 + c]; sm += x; sq = fmaf(x, x, sq); }
        sm += __shfl_xor(sm, 1); sm += __shfl_xor(sm, 2); sm += __shfl_xor(sm, 4);
        sq += __shfl_xor(sq, 1); sq += __shfl_xor(sq, 2); sq += __shfl_xor(sq, 4);
        float m = sm * (1.f / 128.f);
        float rs = rsqrtf(sq * (1.f / 128.f) - m * m + 1e-5f);
        #pragma unroll
        for (int c = 0; c < 16; ++c) { int ix = r * 128 + c0 + c; sa[ix] = (sa[ix] - m) * rs; }
        sm = 0.f; sq = 0.f;
        #pragma unroll
        for (int c = 0; c < 16; ++c) { float x = ss[r * 128 + c0 + c]; sm += x; sq = fmaf(x, x, sq); }
        sm += __shfl_xor(sm, 1); sm += __shfl_xor(sm, 2); sm += __shfl_xor(sm, 4);
        sq += __shfl_xor(sq, 1); sq += __shfl_xor(sq, 2); sq += __shfl_xor(sq, 4);
        m = sm * (1.f / 128.f);
        rs = rsqrtf(sq * (1.f / 128.f) - m * m + 1e-5f);
        #pragma unroll
        for (int c = 0; c < 16; ++c) { int ix = r * 128 + c0 + c; ss[ix] = (ss[ix] - m) * rs; }
    }
    __syncthreads();
    const int o = tid & 127;
    const int i0 = (tid >> 7) * 16;
    {   // An = sigmoid(sn@Wg1+bg1) * an + sn@Ws1
        float accg[16], accs[16];
        #pragma unroll
        for (int i = 0; i < 16; ++i) { accg[i] = 0.f; accs[i] = 0.f; }
        for (int c = 0; c < 128; ++c) {
            float wg = Wg1[c * 128 + o];
            float ws = Ws1[c * 128 + o];
            #pragma unroll
            for (int i = 0; i < 16; ++i) {
                float s = ss[(i0 + i) * 128 + c];
                accg[i] = fmaf(s, wg, accg[i]);
                accs[i] = fmaf(s, ws, accs[i]);
            }
        }
        float bgo = bg1[o];
        #pragma unroll
        for (int i = 0; i < 16; ++i)
            san[(i0 + i) * 128 + o] = sigmoidf_(accg[i] + bgo) * sa[(i0 + i) * 128 + o] + accs[i];
    }
    __syncthreads();
    {   // Q,K,V,G projections
        float aq[16], ak[16], av[16], ag[16];
        #pragma unroll
        for (int i = 0; i < 16; ++i) { aq[i] = 0.f; ak[i] = 0.f; av[i] = 0.f; ag[i] = 0.f; }
        for (int c = 0; c < 128; ++c) {
            float wq = Wq[c * 128 + o], wk = Wk[c * 128 + o];
            float wv = Wv[c * 128 + o], wg = Wga[c * 128 + o];
            #pragma unroll
            for (int i = 0; i < 16; ++i) {
                float x = san[(i0 + i) * 128 + c];
                aq[i] = fmaf(x, wq, aq[i]);
                ak[i] = fmaf(x, wk, ak[i]);
                av[i] = fmaf(x, wv, av[i]);
                ag[i] = fmaf(x, wg, ag[i]);
            }
        }
        float bqo = bq[o];
        #pragma unroll
        for (int i = 0; i < 16; ++i) {
            long t = t0 + i0 + i;
            Qo[t * 128 + o] = aq[i] + bqo;
            Ko[t * 128 + o] = ak[i];
            Vo[t * 128 + o] = av[i];
            Go[t * 128 + o] = sigmoidf_(ag[i]);
        }
    }
}

// ---------------------------------------------------------------------------
// Kernel 2: gathered pair-bias  B[n,i,j,h] = (LN(Z[q,kc,:]) * g + b) @ Wb
// ---------------------------------------------------------------------------
__global__ __launch_bounds__(256) void k_bias(
    const float* __restrict__ Z, const float* __restrict__ g16, const float* __restrict__ b16,
    const float* __restrict__ Wb, float* __restrict__ biasOut)
{
    const int n = blockIdx.x;
    const int tid = threadIdx.x;
    __shared__ float sWb[64], sg[16], sb[16];
    if (tid < 64) sWb[tid] = Wb[tid];
    if (tid < 16) { sg[tid] = g16[tid]; sb[tid] = b16[tid]; }
    __syncthreads();
    for (int p = 0; p < 16; ++p) {
        int pair = tid + 256 * p;       // 32*128 pairs
        int i = pair >> 7, j = pair & 127;
        int kr = n * 32 - 48 + j;
        int kc = min(max(kr, 0), LL - 1);
        const float4* z4 = (const float4*)(Z + ((long)(n * 32 + i) * LL + kc) * 16);
        float zv[16];
        #pragma unroll
        for (int w = 0; w < 4; ++w) {
            float4 v = z4[w];
            zv[w * 4 + 0] = v.x; zv[w * 4 + 1] = v.y; zv[w * 4 + 2] = v.z; zv[w * 4 + 3] = v.w;
        }
        float sm = 0.f, sq = 0.f;
        #pragma unroll
        for (int cp = 0; cp < 16; ++cp) { sm += zv[cp]; sq = fmaf(zv[cp], zv[cp], sq); }
        float m = sm * (1.f / 16.f);
        float rs = rsqrtf(sq * (1.f / 16.f) - m * m + 1e-5f);
        float b0 = 0.f, b1 = 0.f, b2 = 0.f, b3 = 0.f;
        #pragma unroll
        for (int cp = 0; cp < 16; ++cp) {
            float zn = (zv[cp] - m) * rs * sg[cp] + sb[cp];
            b0 = fmaf(zn, sWb[cp * 4 + 0], b0);
            b1 = fmaf(zn, sWb[cp * 4 + 1], b1);
            b2 = fmaf(zn, sWb[cp * 4 + 2], b2);
            b3 = fmaf(zn, sWb[cp * 4 + 3], b3);
        }
        float4* outp = (float4*)(biasOut + ((long)(n * 32 + i) * 128 + j) * 4);
        *outp = make_float4(b0, b1, b2, b3);
    }
}

// ---------------------------------------------------------------------------
// Kernel 3: windowed attention, one block per (n,h,d).  AF = G * (softmax@V)
// ---------------------------------------------------------------------------
__global__ __launch_bounds__(256) void k_attn(
    const float* __restrict__ Qg, const float* __restrict__ Kg, const float* __restrict__ Vg,
    const float* __restrict__ Gg, const float* __restrict__ biasB, const float* __restrict__ maskK,
    float* __restrict__ AFo)
{
    const int n = blockIdx.x, h = blockIdx.y, d = blockIdx.z;
    const int tid = threadIdx.x;
    __shared__ float ksh[128 * 33];
    __shared__ float vsh[128 * 33];
    __shared__ float qsh[32 * 33];
    __shared__ float sc[32 * 129];
    const long tb = (long)d * LL;
    {   // load K,V window (padded stride 33) and scaled Q
        int j = tid >> 1, c0 = (tid & 1) * 16;
        int kr = n * 32 - 48 + j;
        int kc = min(max(kr, 0), LL - 1);
        const float* kp = Kg + (tb + kc) * 128 + h * 32 + c0;
        const float* vp = Vg + (tb + kc) * 128 + h * 32 + c0;
        #pragma unroll
        for (int c = 0; c < 16; c += 4) {
            float4 a = *(const float4*)(kp + c);
            float4 b = *(const float4*)(vp + c);
            ksh[j * 33 + c0 + c + 0] = a.x; ksh[j * 33 + c0 + c + 1] = a.y;
            ksh[j * 33 + c0 + c + 2] = a.z; ksh[j * 33 + c0 + c + 3] = a.w;
            vsh[j * 33 + c0 + c + 0] = b.x; vsh[j * 33 + c0 + c + 1] = b.y;
            vsh[j * 33 + c0 + c + 2] = b.z; vsh[j * 33 + c0 + c + 3] = b.w;
        }
        int i = tid >> 3, c1 = (tid & 7) * 4;
        float4 q = *(const float4*)(Qg + (tb + n * 32 + i) * 128 + h * 32 + c1);
        const float s32 = 0.17677669529663687f;  // 1/sqrt(32)
        qsh[i * 33 + c1 + 0] = q.x * s32; qsh[i * 33 + c1 + 1] = q.y * s32;
        qsh[i * 33 + c1 + 2] = q.z * s32; qsh[i * 33 + c1 + 3] = q.w * s32;
    }
    __syncthreads();
    {   // scores: thread owns column j, 16 query rows
        const int j = tid & 127, i0 = (tid >> 7) * 16;
        float acc[16];
        #pragma unroll
        for (int i = 0; i < 16; ++i) acc[i] = 0.f;
        for (int c = 0; c < 32; ++c) {
            float kv = ksh[j * 33 + c];
            #pragma unroll
            for (int i = 0; i < 16; ++i)
                acc[i] = fmaf(qsh[(i0 + i) * 33 + c], kv, acc[i]);
        }
        float mk = maskK[n * 128 + j] * 1e9f;
        const float* bp = biasB + ((long)(n * 32 + i0) * 128 + j) * 4 + h;
        #pragma unroll
        for (int i = 0; i < 16; ++i)
            sc[(i0 + i) * 129 + j] = acc[i] + bp[(long)i * 512] - mk;
    }
    __syncthreads();
    {   // softmax over j per row (8 lanes per row)
        const int r = tid >> 3, j0 = (tid & 7) * 16;
        float mx = -3.4e38f;
        #pragma unroll
        for (int e = 0; e < 16; ++e) mx = fmaxf(mx, sc[r * 129 + j0 + e]);
        mx = fmaxf(mx, __shfl_xor(mx, 1));
        mx = fmaxf(mx, __shfl_xor(mx, 2));
        mx = fmaxf(mx, __shfl_xor(mx, 4));
        float pv[16];
        float sm = 0.f;
        #pragma unroll
        for (int e = 0; e < 16; ++e) { float p = expf(sc[r * 129 + j0 + e] - mx); pv[e] = p; sm += p; }
        sm += __shfl_xor(sm, 1); sm += __shfl_xor(sm, 2); sm += __shfl_xor(sm, 4);
        float inv = 1.f / sm;
        #pragma unroll
        for (int e = 0; e < 16; ++e) sc[r * 129 + j0 + e] = pv[e] * inv;
    }
    __syncthreads();
    {   // PV + G-gate + store
        const int c = tid & 31, ig = tid >> 5;
        float acc[4];
        #pragma unroll
        for (int ii = 0; ii < 4; ++ii) acc[ii] = 0.f;
        for (int j = 0; j < 128; ++j) {
            float v = vsh[j * 33 + c];
            #pragma unroll
            for (int ii = 0; ii < 4; ++ii)
                acc[ii] = fmaf(sc[(ig * 4 + ii) * 129 + j], v, acc[ii]);
        }
        #pragma unroll
        for (int ii = 0; ii < 4; ++ii) {
            long t = tb + n * 32 + ig * 4 + ii;
            float g = Gg[t * 128 + h * 32 + c];
            AFo[t * 128 + h * 32 + c] = g * acc[ii];
        }
    }
}

// ---------------------------------------------------------------------------
// Kernel 4: af@Wa, output gate, first residual.  A written to d_out.
// ---------------------------------------------------------------------------
__global__ __launch_bounds__(256) void k_post1(
    const float* __restrict__ AF, const float* __restrict__ S_I, const float* __restrict__ A_I,
    const float* __restrict__ Wa, const float* __restrict__ Wop, const float* __restrict__ bop,
    float* __restrict__ Aout)
{
    __shared__ float saf[32 * 128];
    __shared__ float ssi[32 * 128];
    const int tid = threadIdx.x;
    const long t0 = (long)blockIdx.x * 32;
    {
        const float4* F4 = (const float4*)(AF + t0 * 128);
        const float4* S4 = (const float4*)(S_I + t0 * 128);
        float4* f4 = (float4*)saf;
        float4* s4 = (float4*)ssi;
        #pragma unroll
        for (int k2 = 0; k2 < 4; ++k2) {
            f4[tid + 256 * k2] = F4[tid + 256 * k2];
            s4[tid + 256 * k2] = S4[tid + 256 * k2];
        }
    }
    __syncthreads();
    const int o = tid & 127, i0 = (tid >> 7) * 16;
    float a1[16], a2[16];
    #pragma unroll
    for (int i = 0; i < 16; ++i) { a1[i] = 0.f; a2[i] = 0.f; }
    for (int c = 0; c < 128; ++c) {
        float w1 = Wa[c * 128 + o];
        float w2 = Wop[c * 128 + o];
        #pragma unroll
        for (int i = 0; i < 16; ++i) {
            a1[i] = fmaf(saf[(i0 + i) * 128 + c], w1, a1[i]);
            a2[i] = fmaf(ssi[(i0 + i) * 128 + c], w2, a2[i]);
        }
    }
    float bo = bop[o];
    #pragma unroll
    for (int i = 0; i < 16; ++i) {
        long t = t0 + i0 + i;
        Aout[t * 128 + o] = A_I[t * 128 + o] + sigmoidf_(a2[i] + bo) * a1[i];
    }
}

// ---------------------------------------------------------------------------
// Kernel 5: adaLN2 + SwiGLU transition + gated residual -> final output
// ---------------------------------------------------------------------------
__global__ __launch_bounds__(256) void k_post2(
    const float* __restrict__ Ain, const float* __restrict__ S_I,
    const float* __restrict__ Wg2, const float* __restrict__ bg2, const float* __restrict__ Ws2,
    const float* __restrict__ Wsw, const float* __restrict__ Wlin,
    const float* __restrict__ ctWg, const float* __restrict__ ctbg,
    const float* __restrict__ Wout2, float* __restrict__ Out)
{
    __shared__ float smem[32 * 128 * 3];  // 48 KB
    float* sA = smem;          // LN(A) -> an2
    float* sS = smem + 4096;   // raw S -> sn ; later overwritten by b
    float* sb = smem + 4096;   // b[32][256]
    const int tid = threadIdx.x;
    const long t0 = (long)blockIdx.x * 32;
    {
        const float4* A4 = (const float4*)(Ain + t0 * 128);
        const float4* S4 = (const float4*)(S_I + t0 * 128);
        float4* a4 = (float4*)sA;
        float4* s4 = (float4*)sS;
        #pragma unroll
        for (int k2 = 0; k2 < 4; ++k2) {
            a4[tid + 256 * k2] = A4[tid + 256 * k2];
            s4[tid + 256 * k2] = S4[tid + 256 * k2];
        }
    }
    __syncthreads();
    {   // LN(A) in place
        const int r = tid >> 3, c0 = (tid & 7) * 16;
        float sm = 0.f, sq = 0.f;
        #pragma unroll
        for (int c = 0; c < 16; ++c) { float x = sA[r * 128 + c0 + c]; sm += x; sq = fmaf(x, x, sq); }
        sm += __shfl_xor(sm, 1); sm += __shfl_xor(sm, 2); sm += __shfl_xor(sm, 4);
        sq += __shfl_xor(sq, 1); sq += __shfl_xor(sq, 2); sq += __shfl_xor(sq, 4);
        float m = sm * (1.f / 128.f);
        float rs = rsqrtf(sq * (1.f / 128.f) - m * m + 1e-5f);
        #pragma unroll
        for (int c = 0; c < 16; ++c) { int ix = r * 128 + c0 + c; sA[ix] = (sA[ix] - m) * rs; }
    }
    const int o = tid & 127, i0 = (tid >> 7) * 16;
    float g2[16];
    {   // ct gate from raw S (before S is normalized in place)
        float acc[16];
        #pragma unroll
        for (int i = 0; i < 16; ++i) acc[i] = 0.f;
        for (int c = 0; c < 128; ++c) {
            float w = ctWg[c * 128 + o];
            #pragma unroll
            for (int i = 0; i < 16; ++i)
                acc[i] = fmaf(sS[(i0 + i) * 128 + c], w, acc[i]);
        }
        float bo = ctbg[o];
        #pragma unroll
        for (int i = 0; i < 16; ++i) g2[i] = sigmoidf_(acc[i] + bo);
    }
    __syncthreads();
    {   // LN(S) in place
        const int r = tid >> 3, c0 = (tid & 7) * 16;
        float sm = 0.f, sq = 0.f;
        #pragma unroll
        for (int c = 0; c < 16; ++c) { float x = sS[r * 128 + c0 + c]; sm += x; sq = fmaf(x, x, sq); }
        sm += __shfl_xor(sm, 1); sm += __shfl_xor(sm, 2); sm += __shfl_xor(sm, 4);
        sq += __shfl_xor(sq, 1); sq += __shfl_xor(sq, 2); sq += __shfl_xor(sq, 4);
        float m = sm * (1.f / 128.f);
        float rs = rsqrtf(sq * (1.f / 128.f) - m * m + 1e-5f);
        #pragma unroll
        for (int c = 0; c < 16; ++c) { int ix = r * 128 + c0 + c; sS[ix] = (sS[ix] - m) * rs; }
    }
    __syncthreads();
    {   // an2 = sigmoid(sn@Wg2+bg2)*LN(A) + sn@Ws2   (written over sA)
        float accg[16], accs[16];
        #pragma unroll
        for (int i = 0; i < 16; ++i) { accg[i] = 0.f; accs[i] = 0.f; }
        for (int c = 0; c < 128; ++c) {
            float wg = Wg2[c * 128 + o];
            float ws = Ws2[c * 128 + o];
            #pragma unroll
            for (int i = 0; i < 16; ++i) {
                float s = sS[(i0 + i) * 128 + c];
                accg[i] = fmaf(s, wg, accg[i]);
                accs[i] = fmaf(s, ws, accs[i]);
            }
        }
        float bo = bg2[o];
        #pragma unroll
        for (int i = 0; i < 16; ++i) {
            int ix = (i0 + i) * 128 + o;
            sA[ix] = sigmoidf_(accg[i] + bo) * sA[ix] + accs[i];
        }
    }
    __syncthreads();
    {   // b = silu(an2@Wsw) * (an2@Wlin), thread owns one of 256 cols
        float asw[32], alin[32];
        #pragma unroll
        for (int i = 0; i < 32; ++i) { asw[i] = 0.f; alin[i] = 0.f; }
        const int o2 = tid;
        for (int c = 0; c < 128; ++c) {
            float w1 = Wsw[c * 256 + o2];
            float w2 = Wlin[c * 256 + o2];
            #pragma unroll
            for (int i = 0; i < 32; ++i) {
                float x = sA[i * 128 + c];
                asw[i] = fmaf(x, w1, asw[i]);
                alin[i] = fmaf(x, w2, alin[i]);
            }
        }
        __syncthreads();  // all reads of sS(an2-phase inputs) done; safe to overwrite with b
        #pragma unroll
        for (int i = 0; i < 32; ++i) {
            float x = asw[i];
            sb[i * 256 + o2] = (x / (1.f + expf(-x))) * alin[i];
        }
    }
    __syncthreads();
    {   // out = A + g2 * (b @ Wout2)
        float acc[16];
        #pragma unroll
        for (int i = 0; i < 16; ++i) acc[i] = 0.f;
        for (int k2 = 0; k2 < 256; ++k2) {
            float w = Wout2[k2 * 128 + o];
            #pragma unroll
            for (int i = 0; i < 16; ++i)
                acc[i] = fmaf(sb[(i0 + i) * 256 + k2], w, acc[i]);
        }
        #pragma unroll
        for (int i = 0; i < 16; ++i) {
            long t = t0 + i0 + i;
            Out[t * 128 + o] = Ain[t * 128 + o] + g2[i] * acc[i];
        }
    }
}

// ---------------------------------------------------------------------------
extern "C" void kernel_launch(void* const* d_in, const int* in_sizes, int n_in,
                              void* d_out, int out_size, void* d_ws, size_t ws_size,
                              hipStream_t stream)
{
    const float* A_I  = (const float*)d_in[0];
    const float* S_I  = (const float*)d_in[1];
    const float* Z    = (const float*)d_in[2];
    // d_in[3] indicesQ, d_in[4] indicesK: analytic (identity / clip window)
    // d_in[5] maskQ_float: all zeros (unused)
    const float* maskK = (const float*)d_in[6];
    const float* a1Wg = (const float*)d_in[7];
    const float* a1bg = (const float*)d_in[8];
    const float* a1Ws = (const float*)d_in[9];
    const float* Wq   = (const float*)d_in[10];
    const float* bq   = (const float*)d_in[11];
    const float* Wk   = (const float*)d_in[12];
    const float* Wv   = (const float*)d_in[13];
    const float* ln0g = (const float*)d_in[14];
    const float* ln0b = (const float*)d_in[15];
    const float* Wb   = (const float*)d_in[16];
    const float* Wga  = (const float*)d_in[17];
    const float* Wa   = (const float*)d_in[18];
    const float* Wop  = (const float*)d_in[19];
    const float* bop  = (const float*)d_in[20];
    const float* a2Wg = (const float*)d_in[21];
    const float* a2bg = (const float*)d_in[22];
    const float* a2Ws = (const float*)d_in[23];
    const float* Wsw  = (const float*)d_in[24];
    const float* Wlin = (const float*)d_in[25];
    const float* ctWg = (const float*)d_in[26];
    const float* ctbg = (const float*)d_in[27];
    const float* Wout2 = (const float*)d_in[28];
    float* out = (float*)d_out;

    float* ws = (float*)d_ws;
    const size_t NTC = (size_t)DL * 128;   // 2,097,152 floats per (D,L,C) tensor
    float* Qb = ws;            // also reused as AF after attention (see k_attn aliasing note)
    float* Kb = Qb + NTC;
    float* Vb = Kb + NTC;
    float* Gb = Vb + NTC;
    float* BB = Gb + NTC;      // bias: 64*32*128*4 = 1,048,576 floats
    // AF aliases Qb: each attention block reads exactly the Q channels (t, h*32..)
    // that it later overwrites with AF, with __syncthreads in between -> safe.
    float* AF = Qb;
    // A (post first residual) lives in d_out; k_post2 reads it before overwriting
    // each element within the same thread.

    k_adaln_qkvg<<<DL / 32, 256, 0, stream>>>(A_I, S_I, a1Wg, a1bg, a1Ws,
                                              Wq, bq, Wk, Wv, Wga, Qb, Kb, Vb, Gb);
    k_bias<<<NQB, 256, 0, stream>>>(Z, ln0g, ln0b, Wb, BB);
    k_attn<<<dim3(NQB, 4, 8), 256, 0, stream>>>(Qb, Kb, Vb, Gb, BB, maskK, AF);
    k_post1<<<DL / 32, 256, 0, stream>>>(AF, S_I, A_I, Wa, Wop, bop, out);
    k_post2<<<DL / 32, 256, 0, stream>>>(out, S_I, a2Wg, a2bg, a2Ws,
                                         Wsw, Wlin, ctWg, ctbg, Wout2, out);
}

// Round 2
// 175.769 us; speedup vs baseline: 1.6560x; 1.6560x over previous
//
#include <hip/hip_runtime.h>

// Problem constants
#define DL 16384   // D*L tokens
#define LL 2048
#define NQB 64     // NQ
#define QBS 32     // QB
#define KBS 128    // KB

typedef __attribute__((ext_vector_type(8))) short short8;
typedef __attribute__((ext_vector_type(4))) float f32x4;

__device__ __forceinline__ float sigmoidf_(float x) { return 1.f / (1.f + expf(-x)); }

__device__ __forceinline__ short f2bf(float f) {
    union { float f; unsigned u; } v; v.f = f;
    unsigned r = (v.u + 0x7FFFu + ((v.u >> 16) & 1u)) >> 16;
    return (short)r;
}
__device__ __forceinline__ float bf2f(short h) {
    union { unsigned u; float f; } v; v.u = ((unsigned)(unsigned short)h) << 16;
    return v.f;
}

// fragment helpers (cl = lane&15, kg = lane>>4 must be in scope)
#define AFRAG(buf, stride, r0, kk) (*(const short8*)&(buf)[(size_t)((r0) + cl) * (stride) + (kk) * 32 + kg * 8])
#define WFRAG(Wt, K, n0, kk) (*(const short8*)((Wt) + (size_t)((n0) + cl) * (K) + (kk) * 32 + kg * 8))
#define MFMA(acc, a, b) acc = __builtin_amdgcn_mfma_f32_16x16x32_bf16(a, b, acc, 0, 0, 0)

// ---------------------------------------------------------------------------
// Kernel 0: weight prep — bf16 transposed copies of all GEMM weights.
// Wt[o*K + c] = (bf16) W[c*N + o]
// ---------------------------------------------------------------------------
__global__ __launch_bounds__(256) void k_wprep(
    const float* __restrict__ W0, const float* __restrict__ W1, const float* __restrict__ W2,
    const float* __restrict__ W3, const float* __restrict__ W4, const float* __restrict__ W5,
    const float* __restrict__ W6, const float* __restrict__ W7, const float* __restrict__ W8,
    const float* __restrict__ W9, const float* __restrict__ W10,
    const float* __restrict__ Wsw, const float* __restrict__ Wlin, const float* __restrict__ Wout2,
    short* __restrict__ out)
{
    const int b = blockIdx.x;
    const int tid = threadIdx.x;
    if (b < 704) {                       // 11 matrices of 128x128
        int m = b >> 6;
        int e = ((b & 63) << 8) + tid;   // 0..16383
        const float* W;
        switch (m) {
            case 0: W = W0; break; case 1: W = W1; break; case 2: W = W2; break;
            case 3: W = W3; break; case 4: W = W4; break; case 5: W = W5; break;
            case 6: W = W6; break; case 7: W = W7; break; case 8: W = W8; break;
            case 9: W = W9; break; default: W = W10; break;
        }
        int o = e >> 7, c = e & 127;
        out[m * 16384 + e] = f2bf(W[c * 128 + o]);
    } else if (b < 832) {                // Wsw 128x256 -> [256][128]
        int e = ((b - 704) << 8) + tid;  // 0..32767
        int o = e >> 7, c = e & 127;
        out[180224 + e] = f2bf(Wsw[c * 256 + o]);
    } else if (b < 960) {                // Wlin
        int e = ((b - 832) << 8) + tid;
        int o = e >> 7, c = e & 127;
        out[212992 + e] = f2bf(Wlin[c * 256 + o]);
    } else {                             // Wout2 256x128 -> [128][256]
        int e = ((b - 960) << 8) + tid;
        int o = e >> 8, c = e & 255;
        out[245760 + e] = f2bf(Wout2[c * 128 + o]);
    }
}

// ---------------------------------------------------------------------------
// Kernel 1: adaLN1 + QKV+G projections via MFMA.  64 tokens / block.
// ---------------------------------------------------------------------------
__global__ __launch_bounds__(256) void k_adaln_qkvg(
    const float* __restrict__ A_I, const float* __restrict__ S_I,
    const short* __restrict__ Wg1t, const short* __restrict__ Ws1t,
    const short* __restrict__ Wqt, const short* __restrict__ Wkt,
    const short* __restrict__ Wvt, const short* __restrict__ Wgat,
    const float* __restrict__ bg1, const float* __restrict__ bq,
    float* __restrict__ Qo, float* __restrict__ Ko, float* __restrict__ Vo, float* __restrict__ Go)
{
    __shared__ short sAr[64 * 136];   // raw A bf16
    __shared__ short sSn[64 * 136];   // LN(S) bf16
    __shared__ short sAn[64 * 136];   // An bf16
    __shared__ float sMean[64], sRstd[64];
    const int tid = threadIdx.x;
    const int lane = tid & 63;
    const long t0 = (long)blockIdx.x * 64;

    {   // P0: load A,S; LN stats; stage bf16
        const int row = tid >> 2, seg = tid & 3;
        const float* ap = A_I + (t0 + row) * 128 + seg * 32;
        const float* sp = S_I + (t0 + row) * 128 + seg * 32;
        float av[32], sv[32];
        #pragma unroll
        for (int u = 0; u < 8; ++u) {
            float4 a4 = ((const float4*)ap)[u];
            float4 s4 = ((const float4*)sp)[u];
            av[4*u] = a4.x; av[4*u+1] = a4.y; av[4*u+2] = a4.z; av[4*u+3] = a4.w;
            sv[4*u] = s4.x; sv[4*u+1] = s4.y; sv[4*u+2] = s4.z; sv[4*u+3] = s4.w;
        }
        float am = 0.f, aq = 0.f, sm = 0.f, sq = 0.f;
        #pragma unroll
        for (int u = 0; u < 32; ++u) {
            am += av[u]; aq = fmaf(av[u], av[u], aq);
            sm += sv[u]; sq = fmaf(sv[u], sv[u], sq);
        }
        am += __shfl_xor(am, 1); am += __shfl_xor(am, 2);
        aq += __shfl_xor(aq, 1); aq += __shfl_xor(aq, 2);
        sm += __shfl_xor(sm, 1); sm += __shfl_xor(sm, 2);
        sq += __shfl_xor(sq, 1); sq += __shfl_xor(sq, 2);
        float amean = am * (1.f / 128.f);
        float arstd = rsqrtf(aq * (1.f / 128.f) - amean * amean + 1e-5f);
        float smean = sm * (1.f / 128.f);
        float srstd = rsqrtf(sq * (1.f / 128.f) - smean * smean + 1e-5f);
        if ((tid & 3) == 0) { sMean[row] = amean; sRstd[row] = arstd; }
        #pragma unroll
        for (int g = 0; g < 4; ++g) {
            short8 pa, ps;
            #pragma unroll
            for (int e = 0; e < 8; ++e) {
                pa[e] = f2bf(av[g * 8 + e]);
                ps[e] = f2bf((sv[g * 8 + e] - smean) * srstd);
            }
            *(short8*)&sAr[row * 136 + seg * 32 + g * 8] = pa;
            *(short8*)&sSn[row * 136 + seg * 32 + g * 8] = ps;
        }
    }
    __syncthreads();
    const int w = tid >> 6, wr0 = w * 16;
    const int cl = lane & 15, kg = lane >> 4;
    {   // P1: An = sigmoid(sn@Wg1+bg1)*an + sn@Ws1
        for (int nt = 0; nt < 8; ++nt) {
            f32x4 ag = {0.f, 0.f, 0.f, 0.f}, as = {0.f, 0.f, 0.f, 0.f};
            const int n0 = nt * 16;
            #pragma unroll
            for (int kk = 0; kk < 4; ++kk) {
                short8 a = AFRAG(sSn, 136, wr0, kk);
                short8 bg = WFRAG(Wg1t, 128, n0, kk);
                short8 bs = WFRAG(Ws1t, 128, n0, kk);
                MFMA(ag, a, bg);
                MFMA(as, a, bs);
            }
            const int col = n0 + cl;
            float bgc = bg1[col];
            #pragma unroll
            for (int i = 0; i < 4; ++i) {
                int r = wr0 + kg * 4 + i;
                float an = (bf2f(sAr[r * 136 + col]) - sMean[r]) * sRstd[r];
                float An = sigmoidf_(ag[i] + bgc) * an + as[i];
                sAn[r * 136 + col] = f2bf(An);
            }
        }
    }
    __syncthreads();
    {   // P2: Q,K,V,G = An @ {Wq,Wk,Wv,Wga}
        for (int nt = 0; nt < 32; ++nt) {
            const short* Wt = (nt < 8) ? Wqt : (nt < 16) ? Wkt : (nt < 24) ? Wvt : Wgat;
            const int n0 = (nt & 7) * 16;
            f32x4 acc = {0.f, 0.f, 0.f, 0.f};
            #pragma unroll
            for (int kk = 0; kk < 4; ++kk) {
                short8 a = AFRAG(sAn, 136, wr0, kk);
                short8 b = WFRAG(Wt, 128, n0, kk);
                MFMA(acc, a, b);
            }
            const int col = n0 + cl;
            #pragma unroll
            for (int i = 0; i < 4; ++i) {
                long t = t0 + wr0 + kg * 4 + i;
                float v = acc[i];
                if (nt < 8)       Qo[t * 128 + col] = v + bq[col];
                else if (nt < 16) Ko[t * 128 + col] = v;
                else if (nt < 24) Vo[t * 128 + col] = v;
                else              Go[t * 128 + col] = sigmoidf_(v);
            }
        }
    }
}

// ---------------------------------------------------------------------------
// Kernel 2: gathered pair-bias  B[n,i,j,h] = (LN(Z[q,kc,:]) * g + b) @ Wb
// ---------------------------------------------------------------------------
__global__ __launch_bounds__(256) void k_bias(
    const float* __restrict__ Z, const float* __restrict__ g16, const float* __restrict__ b16,
    const float* __restrict__ Wb, float* __restrict__ biasOut)
{
    const int n = blockIdx.x;
    const int tid = threadIdx.x;
    __shared__ float sWb[64], sg[16], sb[16];
    if (tid < 64) sWb[tid] = Wb[tid];
    if (tid < 16) { sg[tid] = g16[tid]; sb[tid] = b16[tid]; }
    __syncthreads();
    for (int p = 0; p < 16; ++p) {
        int pair = tid + 256 * p;       // 32*128 pairs
        int i = pair >> 7, j = pair & 127;
        int kr = n * 32 - 48 + j;
        int kc = min(max(kr, 0), LL - 1);
        const float4* z4 = (const float4*)(Z + ((long)(n * 32 + i) * LL + kc) * 16);
        float zv[16];
        #pragma unroll
        for (int w = 0; w < 4; ++w) {
            float4 v = z4[w];
            zv[w * 4 + 0] = v.x; zv[w * 4 + 1] = v.y; zv[w * 4 + 2] = v.z; zv[w * 4 + 3] = v.w;
        }
        float sm = 0.f, sq = 0.f;
        #pragma unroll
        for (int cp = 0; cp < 16; ++cp) { sm += zv[cp]; sq = fmaf(zv[cp], zv[cp], sq); }
        float m = sm * (1.f / 16.f);
        float rs = rsqrtf(sq * (1.f / 16.f) - m * m + 1e-5f);
        float b0 = 0.f, b1 = 0.f, b2 = 0.f, b3 = 0.f;
        #pragma unroll
        for (int cp = 0; cp < 16; ++cp) {
            float zn = (zv[cp] - m) * rs * sg[cp] + sb[cp];
            b0 = fmaf(zn, sWb[cp * 4 + 0], b0);
            b1 = fmaf(zn, sWb[cp * 4 + 1], b1);
            b2 = fmaf(zn, sWb[cp * 4 + 2], b2);
            b3 = fmaf(zn, sWb[cp * 4 + 3], b3);
        }
        float4* outp = (float4*)(biasOut + ((long)(n * 32 + i) * 128 + j) * 4);
        *outp = make_float4(b0, b1, b2, b3);
    }
}

// ---------------------------------------------------------------------------
// Kernel 3: windowed attention, one block per (n,h,d).  AF = G * (softmax@V)
// ---------------------------------------------------------------------------
__global__ __launch_bounds__(256) void k_attn(
    const float* __restrict__ Qg, const float* __restrict__ Kg, const float* __restrict__ Vg,
    const float* __restrict__ Gg, const float* __restrict__ biasB, const float* __restrict__ maskK,
    float* __restrict__ AFo)
{
    const int n = blockIdx.x, h = blockIdx.y, d = blockIdx.z;
    const int tid = threadIdx.x;
    __shared__ float ksh[128 * 33];
    __shared__ float vsh[128 * 33];
    __shared__ float qsh[32 * 33];
    __shared__ float sc[32 * 129];
    const long tb = (long)d * LL;
    {   // load K,V window (padded stride 33) and scaled Q
        int j = tid >> 1, c0 = (tid & 1) * 16;
        int kr = n * 32 - 48 + j;
        int kc = min(max(kr, 0), LL - 1);
        const float* kp = Kg + (tb + kc) * 128 + h * 32 + c0;
        const float* vp = Vg + (tb + kc) * 128 + h * 32 + c0;
        #pragma unroll
        for (int c = 0; c < 16; c += 4) {
            float4 a = *(const float4*)(kp + c);
            float4 b = *(const float4*)(vp + c);
            ksh[j * 33 + c0 + c + 0] = a.x; ksh[j * 33 + c0 + c + 1] = a.y;
            ksh[j * 33 + c0 + c + 2] = a.z; ksh[j * 33 + c0 + c + 3] = a.w;
            vsh[j * 33 + c0 + c + 0] = b.x; vsh[j * 33 + c0 + c + 1] = b.y;
            vsh[j * 33 + c0 + c + 2] = b.z; vsh[j * 33 + c0 + c + 3] = b.w;
        }
        int i = tid >> 3, c1 = (tid & 7) * 4;
        float4 q = *(const float4*)(Qg + (tb + n * 32 + i) * 128 + h * 32 + c1);
        const float s32 = 0.17677669529663687f;  // 1/sqrt(32)
        qsh[i * 33 + c1 + 0] = q.x * s32; qsh[i * 33 + c1 + 1] = q.y * s32;
        qsh[i * 33 + c1 + 2] = q.z * s32; qsh[i * 33 + c1 + 3] = q.w * s32;
    }
    __syncthreads();
    {   // scores: thread owns column j, 16 query rows
        const int j = tid & 127, i0 = (tid >> 7) * 16;
        float acc[16];
        #pragma unroll
        for (int i = 0; i < 16; ++i) acc[i] = 0.f;
        for (int c = 0; c < 32; ++c) {
            float kv = ksh[j * 33 + c];
            #pragma unroll
            for (int i = 0; i < 16; ++i)
                acc[i] = fmaf(qsh[(i0 + i) * 33 + c], kv, acc[i]);
        }
        float mk = maskK[n * 128 + j] * 1e9f;
        const float* bp = biasB + ((long)(n * 32 + i0) * 128 + j) * 4 + h;
        #pragma unroll
        for (int i = 0; i < 16; ++i)
            sc[(i0 + i) * 129 + j] = acc[i] + bp[(long)i * 512] - mk;
    }
    __syncthreads();
    {   // softmax over j per row (8 lanes per row)
        const int r = tid >> 3, j0 = (tid & 7) * 16;
        float mx = -3.4e38f;
        #pragma unroll
        for (int e = 0; e < 16; ++e) mx = fmaxf(mx, sc[r * 129 + j0 + e]);
        mx = fmaxf(mx, __shfl_xor(mx, 1));
        mx = fmaxf(mx, __shfl_xor(mx, 2));
        mx = fmaxf(mx, __shfl_xor(mx, 4));
        float pv[16];
        float sm = 0.f;
        #pragma unroll
        for (int e = 0; e < 16; ++e) { float p = expf(sc[r * 129 + j0 + e] - mx); pv[e] = p; sm += p; }
        sm += __shfl_xor(sm, 1); sm += __shfl_xor(sm, 2); sm += __shfl_xor(sm, 4);
        float inv = 1.f / sm;
        #pragma unroll
        for (int e = 0; e < 16; ++e) sc[r * 129 + j0 + e] = pv[e] * inv;
    }
    __syncthreads();
    {   // PV + G-gate + store
        const int c = tid & 31, ig = tid >> 5;
        float acc[4];
        #pragma unroll
        for (int ii = 0; ii < 4; ++ii) acc[ii] = 0.f;
        for (int j = 0; j < 128; ++j) {
            float v = vsh[j * 33 + c];
            #pragma unroll
            for (int ii = 0; ii < 4; ++ii)
                acc[ii] = fmaf(sc[(ig * 4 + ii) * 129 + j], v, acc[ii]);
        }
        #pragma unroll
        for (int ii = 0; ii < 4; ++ii) {
            long t = tb + n * 32 + ig * 4 + ii;
            float g = Gg[t * 128 + h * 32 + c];
            AFo[t * 128 + h * 32 + c] = g * acc[ii];
        }
    }
}

// ---------------------------------------------------------------------------
// Kernel 4: fused post: af@Wa gate residual + adaLN2 + SwiGLU + ct-gate.
// 64 tokens / block, MFMA everywhere.
// ---------------------------------------------------------------------------
__global__ __launch_bounds__(256) void k_postf(
    const float* __restrict__ AF, const float* __restrict__ S_I, const float* __restrict__ A_I,
    const short* __restrict__ Wat, const short* __restrict__ Wopt, const short* __restrict__ ctWgt,
    const short* __restrict__ Wg2t, const short* __restrict__ Ws2t,
    const short* __restrict__ Wswt, const short* __restrict__ Wlint, const short* __restrict__ Wout2t,
    const float* __restrict__ bop, const float* __restrict__ ctbg, const float* __restrict__ bg2,
    float* __restrict__ Out)
{
    __shared__ __align__(16) char smem[86528];
    short* sAF  = (short*)smem;              // [64][136] bf16 AF       -> reused as sAn2
    short* sS   = (short*)(smem + 17408);    // [64][136] bf16 raw S    -> reused by sB
    short* sSn  = (short*)(smem + 34816);    // [64][136] bf16 LN(S)    (partly reused by sB)
    float* sA   = (float*)(smem + 52224);    // [64][132] f32 A (raw, kept)
    float* sMean = (float*)(smem + 86016);   // [64]
    float* sRstd = (float*)(smem + 86272);   // [64]
    short* sAn2 = sAF;                       // [64][136] bf16 an2
    short* sB   = (short*)(smem + 17408);    // [64][264] bf16 b (33792 B, ends 51200 < 52224)

    const int tid = threadIdx.x;
    const int lane = tid & 63;
    const long t0 = (long)blockIdx.x * 64;

    {   // P0: load AF (->bf16) and S (->raw bf16 + LN bf16)
        const int row = tid >> 2, seg = tid & 3;
        const float* fp = AF + (t0 + row) * 128 + seg * 32;
        const float* sp = S_I + (t0 + row) * 128 + seg * 32;
        float fv[32], sv[32];
        #pragma unroll
        for (int u = 0; u < 8; ++u) {
            float4 a4 = ((const float4*)fp)[u];
            float4 s4 = ((const float4*)sp)[u];
            fv[4*u] = a4.x; fv[4*u+1] = a4.y; fv[4*u+2] = a4.z; fv[4*u+3] = a4.w;
            sv[4*u] = s4.x; sv[4*u+1] = s4.y; sv[4*u+2] = s4.z; sv[4*u+3] = s4.w;
        }
        float sm = 0.f, sq = 0.f;
        #pragma unroll
        for (int u = 0; u < 32; ++u) { sm += sv[u]; sq = fmaf(sv[u], sv[u], sq); }
        sm += __shfl_xor(sm, 1); sm += __shfl_xor(sm, 2);
        sq += __shfl_xor(sq, 1); sq += __shfl_xor(sq, 2);
        float smean = sm * (1.f / 128.f);
        float srstd = rsqrtf(sq * (1.f / 128.f) - smean * smean + 1e-5f);
        #pragma unroll
        for (int g = 0; g < 4; ++g) {
            short8 pf, pr, pn;
            #pragma unroll
            for (int e = 0; e < 8; ++e) {
                float s = sv[g * 8 + e];
                pf[e] = f2bf(fv[g * 8 + e]);
                pr[e] = f2bf(s);
                pn[e] = f2bf((s - smean) * srstd);
            }
            *(short8*)&sAF[row * 136 + seg * 32 + g * 8] = pf;
            *(short8*)&sS [row * 136 + seg * 32 + g * 8] = pr;
            *(short8*)&sSn[row * 136 + seg * 32 + g * 8] = pn;
        }
    }
    __syncthreads();
    const int w = tid >> 6, wr0 = w * 16;
    const int cl = lane & 15, kg = lane >> 4;
    float g2s[32];   // ct gate, persists to P6 (loops fully unrolled -> registers)

    {   // P2: A = A_I + sigmoid(S@Wop+bop) * (AF@Wa);  g2 = sigmoid(S@ctWg+ctbg)
        #pragma unroll
        for (int nt = 0; nt < 8; ++nt) {
            f32x4 aA = {0.f,0.f,0.f,0.f}, aO = {0.f,0.f,0.f,0.f}, aG = {0.f,0.f,0.f,0.f};
            const int n0 = nt * 16;
            #pragma unroll
            for (int kk = 0; kk < 4; ++kk) {
                short8 af = AFRAG(sAF, 136, wr0, kk);
                short8 sf = AFRAG(sS, 136, wr0, kk);
                short8 bA = WFRAG(Wat, 128, n0, kk);
                short8 bO = WFRAG(Wopt, 128, n0, kk);
                short8 bG = WFRAG(ctWgt, 128, n0, kk);
                MFMA(aA, af, bA);
                MFMA(aO, sf, bO);
                MFMA(aG, sf, bG);
            }
            const int col = n0 + cl;
            float bopc = bop[col], ctc = ctbg[col];
            #pragma unroll
            for (int i = 0; i < 4; ++i) {
                int r = wr0 + kg * 4 + i;
                long t = t0 + r;
                float Aval = A_I[t * 128 + col] + sigmoidf_(aO[i] + bopc) * aA[i];
                sA[r * 132 + col] = Aval;
                g2s[nt * 4 + i] = sigmoidf_(aG[i] + ctc);
            }
        }
    }
    __syncthreads();
    {   // P3: LN stats of A rows
        const int row = tid >> 2, seg = tid & 3;
        float m = 0.f, q = 0.f;
        #pragma unroll
        for (int u = 0; u < 8; ++u) {
            float4 v = *(const float4*)&sA[row * 132 + seg * 32 + u * 4];
            m += v.x + v.y + v.z + v.w;
            q = fmaf(v.x, v.x, q); q = fmaf(v.y, v.y, q);
            q = fmaf(v.z, v.z, q); q = fmaf(v.w, v.w, q);
        }
        m += __shfl_xor(m, 1); m += __shfl_xor(m, 2);
        q += __shfl_xor(q, 1); q += __shfl_xor(q, 2);
        float mean = m * (1.f / 128.f);
        float rstd = rsqrtf(q * (1.f / 128.f) - mean * mean + 1e-5f);
        if ((tid & 3) == 0) { sMean[row] = mean; sRstd[row] = rstd; }
    }
    __syncthreads();
    {   // P4: an2 = sigmoid(sn@Wg2+bg2)*LN(A) + sn@Ws2  (writes sAn2 = old sAF)
        for (int nt = 0; nt < 8; ++nt) {
            f32x4 ag = {0.f,0.f,0.f,0.f}, as = {0.f,0.f,0.f,0.f};
            const int n0 = nt * 16;
            #pragma unroll
            for (int kk = 0; kk < 4; ++kk) {
                short8 a = AFRAG(sSn, 136, wr0, kk);
                short8 bg = WFRAG(Wg2t, 128, n0, kk);
                short8 bs = WFRAG(Ws2t, 128, n0, kk);
                MFMA(ag, a, bg);
                MFMA(as, a, bs);
            }
            const int col = n0 + cl;
            float bg2c = bg2[col];
            #pragma unroll
            for (int i = 0; i < 4; ++i) {
                int r = wr0 + kg * 4 + i;
                float lnA = (sA[r * 132 + col] - sMean[r]) * sRstd[r];
                sAn2[r * 136 + col] = f2bf(sigmoidf_(ag[i] + bg2c) * lnA + as[i]);
            }
        }
    }
    __syncthreads();
    {   // P5: b = silu(an2@Wsw) * (an2@Wlin)   (writes sB over sS/sSn region)
        for (int nt = 0; nt < 16; ++nt) {
            f32x4 aw = {0.f,0.f,0.f,0.f}, al = {0.f,0.f,0.f,0.f};
            const int n0 = nt * 16;
            #pragma unroll
            for (int kk = 0; kk < 4; ++kk) {
                short8 a = AFRAG(sAn2, 136, wr0, kk);
                short8 bw = WFRAG(Wswt, 128, n0, kk);
                short8 bl = WFRAG(Wlint, 128, n0, kk);
                MFMA(aw, a, bw);
                MFMA(al, a, bl);
            }
            const int col2 = n0 + cl;
            #pragma unroll
            for (int i = 0; i < 4; ++i) {
                int r = wr0 + kg * 4 + i;
                float x = aw[i];
                float bb = (x / (1.f + expf(-x))) * al[i];
                sB[r * 264 + col2] = f2bf(bb);
            }
        }
    }
    __syncthreads();
    {   // P6: out = A + g2 * (b @ Wout2)
        #pragma unroll
        for (int nt = 0; nt < 8; ++nt) {
            f32x4 acc = {0.f,0.f,0.f,0.f};
            const int n0 = nt * 16;
            #pragma unroll
            for (int kk = 0; kk < 8; ++kk) {
                short8 a = AFRAG(sB, 264, wr0, kk);
                short8 b = WFRAG(Wout2t, 256, n0, kk);
                MFMA(acc, a, b);
            }
            const int col = n0 + cl;
            #pragma unroll
            for (int i = 0; i < 4; ++i) {
                int r = wr0 + kg * 4 + i;
                long t = t0 + r;
                Out[t * 128 + col] = sA[r * 132 + col] + g2s[nt * 4 + i] * acc[i];
            }
        }
    }
}

// ---------------------------------------------------------------------------
extern "C" void kernel_launch(void* const* d_in, const int* in_sizes, int n_in,
                              void* d_out, int out_size, void* d_ws, size_t ws_size,
                              hipStream_t stream)
{
    const float* A_I  = (const float*)d_in[0];
    const float* S_I  = (const float*)d_in[1];
    const float* Z    = (const float*)d_in[2];
    const float* maskK = (const float*)d_in[6];
    const float* a1Wg = (const float*)d_in[7];
    const float* a1bg = (const float*)d_in[8];
    const float* a1Ws = (const float*)d_in[9];
    const float* Wq   = (const float*)d_in[10];
    const float* bq   = (const float*)d_in[11];
    const float* Wk   = (const float*)d_in[12];
    const float* Wv   = (const float*)d_in[13];
    const float* ln0g = (const float*)d_in[14];
    const float* ln0b = (const float*)d_in[15];
    const float* Wb   = (const float*)d_in[16];
    const float* Wga  = (const float*)d_in[17];
    const float* Wa   = (const float*)d_in[18];
    const float* Wop  = (const float*)d_in[19];
    const float* bop  = (const float*)d_in[20];
    const float* a2Wg = (const float*)d_in[21];
    const float* a2bg = (const float*)d_in[22];
    const float* a2Ws = (const float*)d_in[23];
    const float* Wsw  = (const float*)d_in[24];
    const float* Wlin = (const float*)d_in[25];
    const float* ctWg = (const float*)d_in[26];
    const float* ctbg = (const float*)d_in[27];
    const float* Wout2 = (const float*)d_in[28];
    float* out = (float*)d_out;

    float* ws = (float*)d_ws;
    const size_t NTC = (size_t)DL * 128;   // 2,097,152 floats
    float* Qb = ws;
    float* Kb = Qb + NTC;
    float* Vb = Kb + NTC;
    float* Gb = Vb + NTC;
    float* BB = Gb + NTC;                  // 1,048,576 floats
    short* wbt = (short*)(BB + (size_t)NQB * 32 * 128 * 4);   // bf16 transposed weights
    float* AFb = Qb;                        // attention output aliases Qb (safe: per-element RAW within block)

    // bf16 transposed weight offsets (shorts)
    short* Wg1t = wbt + 0 * 16384;
    short* Ws1t = wbt + 1 * 16384;
    short* Wqt  = wbt + 2 * 16384;
    short* Wkt  = wbt + 3 * 16384;
    short* Wvt  = wbt + 4 * 16384;
    short* Wgat = wbt + 5 * 16384;
    short* Wat  = wbt + 6 * 16384;
    short* Wopt = wbt + 7 * 16384;
    short* ctWgt = wbt + 8 * 16384;
    short* Wg2t = wbt + 9 * 16384;
    short* Ws2t = wbt + 10 * 16384;
    short* Wswt = wbt + 180224;
    short* Wlint = wbt + 212992;
    short* Wout2t = wbt + 245760;

    k_wprep<<<1088, 256, 0, stream>>>(a1Wg, a1Ws, Wq, Wk, Wv, Wga, Wa, Wop, ctWg,
                                      a2Wg, a2Ws, Wsw, Wlin, Wout2, wbt);
    k_adaln_qkvg<<<DL / 64, 256, 0, stream>>>(A_I, S_I, Wg1t, Ws1t, Wqt, Wkt, Wvt, Wgat,
                                              a1bg, bq, Qb, Kb, Vb, Gb);
    k_bias<<<NQB, 256, 0, stream>>>(Z, ln0g, ln0b, Wb, BB);
    k_attn<<<dim3(NQB, 4, 8), 256, 0, stream>>>(Qb, Kb, Vb, Gb, BB, maskK, AFb);
    k_postf<<<DL / 64, 256, 0, stream>>>(AFb, S_I, A_I, Wat, Wopt, ctWgt, Wg2t, Ws2t,
                                         Wswt, Wlint, Wout2t, bop, ctbg, a2bg, out);
}

// Round 3
// 115.334 us; speedup vs baseline: 2.5238x; 1.5240x over previous
//
#include <hip/hip_runtime.h>

// Problem constants
#define DL 16384   // D*L tokens
#define LL 2048
#define NQB 64     // NQ
#define QBS 32     // QB
#define KBS 128    // KB

typedef __attribute__((ext_vector_type(8))) short short8;
typedef __attribute__((ext_vector_type(4))) float f32x4;

__device__ __forceinline__ float sigmoidf_(float x) { return 1.f / (1.f + expf(-x)); }

__device__ __forceinline__ short f2bf(float f) {
    union { float f; unsigned u; } v; v.f = f;
    unsigned r = (v.u + 0x7FFFu + ((v.u >> 16) & 1u)) >> 16;
    return (short)r;
}
__device__ __forceinline__ float bf2f(short h) {
    union { unsigned u; float f; } v; v.u = ((unsigned)(unsigned short)h) << 16;
    return v.f;
}

// fragment helpers (cl = lane&15, kg = lane>>4 must be in scope)
#define AFRAG(buf, stride, r0, kk) (*(const short8*)&(buf)[(size_t)((r0) + cl) * (stride) + (kk) * 32 + kg * 8])
#define WFRAG(Wt, K, n0, kk) (*(const short8*)((Wt) + (size_t)((n0) + cl) * (K) + (kk) * 32 + kg * 8))
#define MFMA(acc, a, b) acc = __builtin_amdgcn_mfma_f32_16x16x32_bf16(a, b, acc, 0, 0, 0)

// ---------------------------------------------------------------------------
// Kernel 0: weight prep — bf16 transposed copies of all GEMM weights.
// Wt[o*K + c] = (bf16) W[c*N + o]
// ---------------------------------------------------------------------------
__global__ __launch_bounds__(256) void k_wprep(
    const float* __restrict__ W0, const float* __restrict__ W1, const float* __restrict__ W2,
    const float* __restrict__ W3, const float* __restrict__ W4, const float* __restrict__ W5,
    const float* __restrict__ W6, const float* __restrict__ W7, const float* __restrict__ W8,
    const float* __restrict__ W9, const float* __restrict__ W10,
    const float* __restrict__ Wsw, const float* __restrict__ Wlin, const float* __restrict__ Wout2,
    short* __restrict__ out)
{
    const int b = blockIdx.x;
    const int tid = threadIdx.x;
    if (b < 704) {                       // 11 matrices of 128x128
        int m = b >> 6;
        int e = ((b & 63) << 8) + tid;   // 0..16383
        const float* W;
        switch (m) {
            case 0: W = W0; break; case 1: W = W1; break; case 2: W = W2; break;
            case 3: W = W3; break; case 4: W = W4; break; case 5: W = W5; break;
            case 6: W = W6; break; case 7: W = W7; break; case 8: W = W8; break;
            case 9: W = W9; break; default: W = W10; break;
        }
        int o = e >> 7, c = e & 127;
        out[m * 16384 + e] = f2bf(W[c * 128 + o]);
    } else if (b < 832) {                // Wsw 128x256 -> [256][128]
        int e = ((b - 704) << 8) + tid;  // 0..32767
        int o = e >> 7, c = e & 127;
        out[180224 + e] = f2bf(Wsw[c * 256 + o]);
    } else if (b < 960) {                // Wlin
        int e = ((b - 832) << 8) + tid;
        int o = e >> 7, c = e & 127;
        out[212992 + e] = f2bf(Wlin[c * 256 + o]);
    } else {                             // Wout2 256x128 -> [128][256]
        int e = ((b - 960) << 8) + tid;
        int o = e >> 8, c = e & 255;
        out[245760 + e] = f2bf(Wout2[c * 128 + o]);
    }
}

// ---------------------------------------------------------------------------
// Kernel 1: adaLN1 + QKV+G projections via MFMA.  64 tokens / block.
// Outputs bf16: Q pre-scaled by 1/sqrt(32), K, V, G=sigmoid(.)
// ---------------------------------------------------------------------------
__global__ __launch_bounds__(256) void k_adaln_qkvg(
    const float* __restrict__ A_I, const float* __restrict__ S_I,
    const short* __restrict__ Wg1t, const short* __restrict__ Ws1t,
    const short* __restrict__ Wqt, const short* __restrict__ Wkt,
    const short* __restrict__ Wvt, const short* __restrict__ Wgat,
    const float* __restrict__ bg1, const float* __restrict__ bq,
    short* __restrict__ Qo, short* __restrict__ Ko, short* __restrict__ Vo, short* __restrict__ Go)
{
    __shared__ short sAr[64 * 136];   // raw A bf16
    __shared__ short sSn[64 * 136];   // LN(S) bf16
    __shared__ short sAn[64 * 136];   // An bf16
    __shared__ float sMean[64], sRstd[64];
    const int tid = threadIdx.x;
    const int lane = tid & 63;
    const long t0 = (long)blockIdx.x * 64;

    {   // P0: load A,S; LN stats; stage bf16
        const int row = tid >> 2, seg = tid & 3;
        const float* ap = A_I + (t0 + row) * 128 + seg * 32;
        const float* sp = S_I + (t0 + row) * 128 + seg * 32;
        float av[32], sv[32];
        #pragma unroll
        for (int u = 0; u < 8; ++u) {
            float4 a4 = ((const float4*)ap)[u];
            float4 s4 = ((const float4*)sp)[u];
            av[4*u] = a4.x; av[4*u+1] = a4.y; av[4*u+2] = a4.z; av[4*u+3] = a4.w;
            sv[4*u] = s4.x; sv[4*u+1] = s4.y; sv[4*u+2] = s4.z; sv[4*u+3] = s4.w;
        }
        float am = 0.f, aq = 0.f, sm = 0.f, sq = 0.f;
        #pragma unroll
        for (int u = 0; u < 32; ++u) {
            am += av[u]; aq = fmaf(av[u], av[u], aq);
            sm += sv[u]; sq = fmaf(sv[u], sv[u], sq);
        }
        am += __shfl_xor(am, 1); am += __shfl_xor(am, 2);
        aq += __shfl_xor(aq, 1); aq += __shfl_xor(aq, 2);
        sm += __shfl_xor(sm, 1); sm += __shfl_xor(sm, 2);
        sq += __shfl_xor(sq, 1); sq += __shfl_xor(sq, 2);
        float amean = am * (1.f / 128.f);
        float arstd = rsqrtf(aq * (1.f / 128.f) - amean * amean + 1e-5f);
        float smean = sm * (1.f / 128.f);
        float srstd = rsqrtf(sq * (1.f / 128.f) - smean * smean + 1e-5f);
        if ((tid & 3) == 0) { sMean[row] = amean; sRstd[row] = arstd; }
        #pragma unroll
        for (int g = 0; g < 4; ++g) {
            short8 pa, ps;
            #pragma unroll
            for (int e = 0; e < 8; ++e) {
                pa[e] = f2bf(av[g * 8 + e]);
                ps[e] = f2bf((sv[g * 8 + e] - smean) * srstd);
            }
            *(short8*)&sAr[row * 136 + seg * 32 + g * 8] = pa;
            *(short8*)&sSn[row * 136 + seg * 32 + g * 8] = ps;
        }
    }
    __syncthreads();
    const int w = tid >> 6, wr0 = w * 16;
    const int cl = lane & 15, kg = lane >> 4;
    {   // P1: An = sigmoid(sn@Wg1+bg1)*an + sn@Ws1
        for (int nt = 0; nt < 8; ++nt) {
            f32x4 ag = {0.f, 0.f, 0.f, 0.f}, as = {0.f, 0.f, 0.f, 0.f};
            const int n0 = nt * 16;
            #pragma unroll
            for (int kk = 0; kk < 4; ++kk) {
                short8 a = AFRAG(sSn, 136, wr0, kk);
                short8 bg = WFRAG(Wg1t, 128, n0, kk);
                short8 bs = WFRAG(Ws1t, 128, n0, kk);
                MFMA(ag, a, bg);
                MFMA(as, a, bs);
            }
            const int col = n0 + cl;
            float bgc = bg1[col];
            #pragma unroll
            for (int i = 0; i < 4; ++i) {
                int r = wr0 + kg * 4 + i;
                float an = (bf2f(sAr[r * 136 + col]) - sMean[r]) * sRstd[r];
                float An = sigmoidf_(ag[i] + bgc) * an + as[i];
                sAn[r * 136 + col] = f2bf(An);
            }
        }
    }
    __syncthreads();
    {   // P2: Q,K,V,G = An @ {Wq,Wk,Wv,Wga}  (bf16 stores)
        const float SCL = 0.17677669529663687f;  // 1/sqrt(32)
        for (int nt = 0; nt < 32; ++nt) {
            const short* Wt = (nt < 8) ? Wqt : (nt < 16) ? Wkt : (nt < 24) ? Wvt : Wgat;
            const int n0 = (nt & 7) * 16;
            f32x4 acc = {0.f, 0.f, 0.f, 0.f};
            #pragma unroll
            for (int kk = 0; kk < 4; ++kk) {
                short8 a = AFRAG(sAn, 136, wr0, kk);
                short8 b = WFRAG(Wt, 128, n0, kk);
                MFMA(acc, a, b);
            }
            const int col = n0 + cl;
            #pragma unroll
            for (int i = 0; i < 4; ++i) {
                long t = t0 + wr0 + kg * 4 + i;
                float v = acc[i];
                if (nt < 8)       Qo[t * 128 + col] = f2bf((v + bq[col]) * SCL);
                else if (nt < 16) Ko[t * 128 + col] = f2bf(v);
                else if (nt < 24) Vo[t * 128 + col] = f2bf(v);
                else              Go[t * 128 + col] = f2bf(sigmoidf_(v));
            }
        }
    }
}

// ---------------------------------------------------------------------------
// Kernel 2: gathered pair-bias  BB[n][h][i][j] = ((LN(Z[q,kc,:])*g+b) @ Wb)[h]
// 4 blocks per n (8 query rows each).
// ---------------------------------------------------------------------------
__global__ __launch_bounds__(256) void k_bias(
    const float* __restrict__ Z, const float* __restrict__ g16, const float* __restrict__ b16,
    const float* __restrict__ Wb, float* __restrict__ BB)
{
    const int n = blockIdx.x >> 2;
    const int io = (blockIdx.x & 3) * 8;
    const int tid = threadIdx.x;
    __shared__ float sWb[64], sg[16], sb[16];
    if (tid < 64) sWb[tid] = Wb[tid];
    if (tid < 16) { sg[tid] = g16[tid]; sb[tid] = b16[tid]; }
    __syncthreads();
    for (int p = 0; p < 4; ++p) {
        int pair = tid + 256 * p;        // 8*128 pairs
        int i = io + (pair >> 7), j = pair & 127;
        int kr = n * 32 - 48 + j;
        int kc = min(max(kr, 0), LL - 1);
        const float4* z4 = (const float4*)(Z + ((long)(n * 32 + i) * LL + kc) * 16);
        float zv[16];
        #pragma unroll
        for (int w = 0; w < 4; ++w) {
            float4 v = z4[w];
            zv[w * 4 + 0] = v.x; zv[w * 4 + 1] = v.y; zv[w * 4 + 2] = v.z; zv[w * 4 + 3] = v.w;
        }
        float sm = 0.f, sq = 0.f;
        #pragma unroll
        for (int cp = 0; cp < 16; ++cp) { sm += zv[cp]; sq = fmaf(zv[cp], zv[cp], sq); }
        float m = sm * (1.f / 16.f);
        float rs = rsqrtf(sq * (1.f / 16.f) - m * m + 1e-5f);
        float b0 = 0.f, b1 = 0.f, b2 = 0.f, b3 = 0.f;
        #pragma unroll
        for (int cp = 0; cp < 16; ++cp) {
            float zn = (zv[cp] - m) * rs * sg[cp] + sb[cp];
            b0 = fmaf(zn, sWb[cp * 4 + 0], b0);
            b1 = fmaf(zn, sWb[cp * 4 + 1], b1);
            b2 = fmaf(zn, sWb[cp * 4 + 2], b2);
            b3 = fmaf(zn, sWb[cp * 4 + 3], b3);
        }
        long base = ((long)n * 4) * 4096 + (long)i * 128 + j;   // [n][h][i][j], h stride 4096
        BB[base + 0 * 4096] = b0;
        BB[base + 1 * 4096] = b1;
        BB[base + 2 * 4096] = b2;
        BB[base + 3 * 4096] = b3;
    }
}

// ---------------------------------------------------------------------------
// Kernel 3: windowed attention via MFMA, one block per (n,h,d).
// AF = G * (softmax(QK^T + bias - mask) @ V), all bf16 in/out.
// ---------------------------------------------------------------------------
__global__ __launch_bounds__(256) void k_attn(
    const short* __restrict__ Qg, const short* __restrict__ Kg, const short* __restrict__ Vg,
    const short* __restrict__ Gg, const float* __restrict__ BB, const float* __restrict__ maskK,
    short* __restrict__ AFo)
{
    const int n = blockIdx.x, h = blockIdx.y, d = blockIdx.z;
    const int tid = threadIdx.x;
    const int lane = tid & 63;
    __shared__ short qsh[32 * 40];    // Q rows [q][c], stride 40
    __shared__ short ksh[128 * 40];   // K rows [key][c], stride 40 (B-operand [N][K])
    __shared__ short vts[32 * 136];   // V^T [c][key], stride 136 (B-operand for PV)
    __shared__ float Sf[32 * 132];    // scores f32
    __shared__ short P[32 * 136];     // softmax probs bf16, A-operand layout
    const long tb = (long)d * LL;

    {   // load K rows + V rows (transposed into vts) ; Q rows
        const int j = tid >> 1, half = tid & 1;
        int kr = n * 32 - 48 + j;
        int kc = min(max(kr, 0), LL - 1);
        const short8* kp = (const short8*)(Kg + (tb + kc) * 128 + h * 32 + half * 16);
        const short8* vp = (const short8*)(Vg + (tb + kc) * 128 + h * 32 + half * 16);
        short8 k0 = kp[0], k1 = kp[1];
        short8 v0 = vp[0], v1 = vp[1];
        *(short8*)&ksh[j * 40 + half * 16 + 0] = k0;
        *(short8*)&ksh[j * 40 + half * 16 + 8] = k1;
        #pragma unroll
        for (int e = 0; e < 8; ++e) {
            vts[(half * 16 + e) * 136 + j] = v0[e];
            vts[(half * 16 + 8 + e) * 136 + j] = v1[e];
        }
        if (tid < 64) {
            const int qi = tid >> 1, qh = tid & 1;
            const short8* qp = (const short8*)(Qg + (tb + n * 32 + qi) * 128 + h * 32 + qh * 16);
            short8 q0 = qp[0], q1 = qp[1];
            *(short8*)&qsh[qi * 40 + qh * 16 + 0] = q0;
            *(short8*)&qsh[qi * 40 + qh * 16 + 8] = q1;
        }
    }
    __syncthreads();
    const int w = tid >> 6;
    const int cl = lane & 15, kg = lane >> 4;
    {   // QK^T: wave w handles mt = w&1 (16 q-rows), nts (w>>1)*4..+4 (key tiles)
        const int mt = w & 1, ntb = (w >> 1) * 4;
        #pragma unroll
        for (int nn = 0; nn < 4; ++nn) {
            const int n0 = (ntb + nn) * 16;
            f32x4 s = {0.f, 0.f, 0.f, 0.f};
            short8 a = *(const short8*)&qsh[(mt * 16 + cl) * 40 + kg * 8];
            short8 b = *(const short8*)&ksh[(n0 + cl) * 40 + kg * 8];
            MFMA(s, a, b);
            const int col = n0 + cl;
            float mkj = maskK[n * 128 + col] * 1e9f;
            const float* bp = BB + (((long)n * 4 + h) * 32 + mt * 16 + kg * 4) * 128 + col;
            #pragma unroll
            for (int i = 0; i < 4; ++i)
                Sf[(mt * 16 + kg * 4 + i) * 132 + col] = s[i] + bp[i * 128] - mkj;
        }
    }
    __syncthreads();
    {   // softmax per q-row (8 threads/row), write P bf16
        const int r = tid >> 3, j0 = (tid & 7) * 16;
        float mx = -3.4e38f;
        #pragma unroll
        for (int e = 0; e < 16; ++e) mx = fmaxf(mx, Sf[r * 132 + j0 + e]);
        mx = fmaxf(mx, __shfl_xor(mx, 1));
        mx = fmaxf(mx, __shfl_xor(mx, 2));
        mx = fmaxf(mx, __shfl_xor(mx, 4));
        float pv[16];
        float sm = 0.f;
        #pragma unroll
        for (int e = 0; e < 16; ++e) { float p = expf(Sf[r * 132 + j0 + e] - mx); pv[e] = p; sm += p; }
        sm += __shfl_xor(sm, 1); sm += __shfl_xor(sm, 2); sm += __shfl_xor(sm, 4);
        float inv = 1.f / sm;
        #pragma unroll
        for (int e = 0; e < 16; ++e) P[r * 136 + j0 + e] = f2bf(pv[e] * inv);
    }
    __syncthreads();
    {   // PV: wave w -> (mt = w&1 q-tile, ct = w>>1 c-tile); K=128 over 4 chunks
        const int mt = w & 1, ct = w >> 1;
        f32x4 acc = {0.f, 0.f, 0.f, 0.f};
        #pragma unroll
        for (int kk = 0; kk < 4; ++kk) {
            short8 a = *(const short8*)&P[(mt * 16 + cl) * 136 + kk * 32 + kg * 8];
            short8 b = *(const short8*)&vts[(ct * 16 + cl) * 136 + kk * 32 + kg * 8];
            MFMA(acc, a, b);
        }
        const int col = h * 32 + ct * 16 + cl;
        #pragma unroll
        for (int i = 0; i < 4; ++i) {
            long t = tb + n * 32 + mt * 16 + kg * 4 + i;
            float g = bf2f(Gg[t * 128 + col]);
            AFo[t * 128 + col] = f2bf(g * acc[i]);
        }
    }
}

// ---------------------------------------------------------------------------
// Kernel 4: fused post: af@Wa gate residual + adaLN2 + SwiGLU + ct-gate.
// 64 tokens / block, MFMA everywhere.  AF input is bf16.
// ---------------------------------------------------------------------------
__global__ __launch_bounds__(256) void k_postf(
    const short* __restrict__ AF, const float* __restrict__ S_I, const float* __restrict__ A_I,
    const short* __restrict__ Wat, const short* __restrict__ Wopt, const short* __restrict__ ctWgt,
    const short* __restrict__ Wg2t, const short* __restrict__ Ws2t,
    const short* __restrict__ Wswt, const short* __restrict__ Wlint, const short* __restrict__ Wout2t,
    const float* __restrict__ bop, const float* __restrict__ ctbg, const float* __restrict__ bg2,
    float* __restrict__ Out)
{
    __shared__ __align__(16) char smem[86528];
    short* sAF  = (short*)smem;              // [64][136] bf16 AF       -> reused as sAn2
    short* sS   = (short*)(smem + 17408);    // [64][136] bf16 raw S    -> reused by sB
    short* sSn  = (short*)(smem + 34816);    // [64][136] bf16 LN(S)    (partly reused by sB)
    float* sA   = (float*)(smem + 52224);    // [64][132] f32 A (raw, kept)
    float* sMean = (float*)(smem + 86016);   // [64]
    float* sRstd = (float*)(smem + 86272);   // [64]
    short* sAn2 = sAF;                       // [64][136] bf16 an2
    short* sB   = (short*)(smem + 17408);    // [64][264] bf16 b (33792 B, ends 51200 < 52224)

    const int tid = threadIdx.x;
    const int lane = tid & 63;
    const long t0 = (long)blockIdx.x * 64;

    {   // P0: copy AF (bf16) ; load S -> raw bf16 + LN bf16
        const int row = tid >> 2, seg = tid & 3;
        const short8* fp = (const short8*)(AF + (t0 + row) * 128 + seg * 32);
        #pragma unroll
        for (int g = 0; g < 4; ++g)
            *(short8*)&sAF[row * 136 + seg * 32 + g * 8] = fp[g];
        const float* sp = S_I + (t0 + row) * 128 + seg * 32;
        float sv[32];
        #pragma unroll
        for (int u = 0; u < 8; ++u) {
            float4 s4 = ((const float4*)sp)[u];
            sv[4*u] = s4.x; sv[4*u+1] = s4.y; sv[4*u+2] = s4.z; sv[4*u+3] = s4.w;
        }
        float sm = 0.f, sq = 0.f;
        #pragma unroll
        for (int u = 0; u < 32; ++u) { sm += sv[u]; sq = fmaf(sv[u], sv[u], sq); }
        sm += __shfl_xor(sm, 1); sm += __shfl_xor(sm, 2);
        sq += __shfl_xor(sq, 1); sq += __shfl_xor(sq, 2);
        float smean = sm * (1.f / 128.f);
        float srstd = rsqrtf(sq * (1.f / 128.f) - smean * smean + 1e-5f);
        #pragma unroll
        for (int g = 0; g < 4; ++g) {
            short8 pr, pn;
            #pragma unroll
            for (int e = 0; e < 8; ++e) {
                float s = sv[g * 8 + e];
                pr[e] = f2bf(s);
                pn[e] = f2bf((s - smean) * srstd);
            }
            *(short8*)&sS [row * 136 + seg * 32 + g * 8] = pr;
            *(short8*)&sSn[row * 136 + seg * 32 + g * 8] = pn;
        }
    }
    __syncthreads();
    const int w = tid >> 6, wr0 = w * 16;
    const int cl = lane & 15, kg = lane >> 4;
    float g2s[32];   // ct gate, persists to P6 (loops fully unrolled -> registers)

    {   // P2: A = A_I + sigmoid(S@Wop+bop) * (AF@Wa);  g2 = sigmoid(S@ctWg+ctbg)
        #pragma unroll
        for (int nt = 0; nt < 8; ++nt) {
            f32x4 aA = {0.f,0.f,0.f,0.f}, aO = {0.f,0.f,0.f,0.f}, aG = {0.f,0.f,0.f,0.f};
            const int n0 = nt * 16;
            #pragma unroll
            for (int kk = 0; kk < 4; ++kk) {
                short8 af = AFRAG(sAF, 136, wr0, kk);
                short8 sf = AFRAG(sS, 136, wr0, kk);
                short8 bA = WFRAG(Wat, 128, n0, kk);
                short8 bO = WFRAG(Wopt, 128, n0, kk);
                short8 bG = WFRAG(ctWgt, 128, n0, kk);
                MFMA(aA, af, bA);
                MFMA(aO, sf, bO);
                MFMA(aG, sf, bG);
            }
            const int col = n0 + cl;
            float bopc = bop[col], ctc = ctbg[col];
            #pragma unroll
            for (int i = 0; i < 4; ++i) {
                int r = wr0 + kg * 4 + i;
                long t = t0 + r;
                float Aval = A_I[t * 128 + col] + sigmoidf_(aO[i] + bopc) * aA[i];
                sA[r * 132 + col] = Aval;
                g2s[nt * 4 + i] = sigmoidf_(aG[i] + ctc);
            }
        }
    }
    __syncthreads();
    {   // P3: LN stats of A rows
        const int row = tid >> 2, seg = tid & 3;
        float m = 0.f, q = 0.f;
        #pragma unroll
        for (int u = 0; u < 8; ++u) {
            float4 v = *(const float4*)&sA[row * 132 + seg * 32 + u * 4];
            m += v.x + v.y + v.z + v.w;
            q = fmaf(v.x, v.x, q); q = fmaf(v.y, v.y, q);
            q = fmaf(v.z, v.z, q); q = fmaf(v.w, v.w, q);
        }
        m += __shfl_xor(m, 1); m += __shfl_xor(m, 2);
        q += __shfl_xor(q, 1); q += __shfl_xor(q, 2);
        float mean = m * (1.f / 128.f);
        float rstd = rsqrtf(q * (1.f / 128.f) - mean * mean + 1e-5f);
        if ((tid & 3) == 0) { sMean[row] = mean; sRstd[row] = rstd; }
    }
    __syncthreads();
    {   // P4: an2 = sigmoid(sn@Wg2+bg2)*LN(A) + sn@Ws2  (writes sAn2 = old sAF)
        for (int nt = 0; nt < 8; ++nt) {
            f32x4 ag = {0.f,0.f,0.f,0.f}, as = {0.f,0.f,0.f,0.f};
            const int n0 = nt * 16;
            #pragma unroll
            for (int kk = 0; kk < 4; ++kk) {
                short8 a = AFRAG(sSn, 136, wr0, kk);
                short8 bg = WFRAG(Wg2t, 128, n0, kk);
                short8 bs = WFRAG(Ws2t, 128, n0, kk);
                MFMA(ag, a, bg);
                MFMA(as, a, bs);
            }
            const int col = n0 + cl;
            float bg2c = bg2[col];
            #pragma unroll
            for (int i = 0; i < 4; ++i) {
                int r = wr0 + kg * 4 + i;
                float lnA = (sA[r * 132 + col] - sMean[r]) * sRstd[r];
                sAn2[r * 136 + col] = f2bf(sigmoidf_(ag[i] + bg2c) * lnA + as[i]);
            }
        }
    }
    __syncthreads();
    {   // P5: b = silu(an2@Wsw) * (an2@Wlin)   (writes sB over sS/sSn region)
        for (int nt = 0; nt < 16; ++nt) {
            f32x4 aw = {0.f,0.f,0.f,0.f}, al = {0.f,0.f,0.f,0.f};
            const int n0 = nt * 16;
            #pragma unroll
            for (int kk = 0; kk < 4; ++kk) {
                short8 a = AFRAG(sAn2, 136, wr0, kk);
                short8 bw = WFRAG(Wswt, 128, n0, kk);
                short8 bl = WFRAG(Wlint, 128, n0, kk);
                MFMA(aw, a, bw);
                MFMA(al, a, bl);
            }
            const int col2 = n0 + cl;
            #pragma unroll
            for (int i = 0; i < 4; ++i) {
                int r = wr0 + kg * 4 + i;
                float x = aw[i];
                float bb = (x / (1.f + expf(-x))) * al[i];
                sB[r * 264 + col2] = f2bf(bb);
            }
        }
    }
    __syncthreads();
    {   // P6: out = A + g2 * (b @ Wout2)
        #pragma unroll
        for (int nt = 0; nt < 8; ++nt) {
            f32x4 acc = {0.f,0.f,0.f,0.f};
            const int n0 = nt * 16;
            #pragma unroll
            for (int kk = 0; kk < 8; ++kk) {
                short8 a = AFRAG(sB, 264, wr0, kk);
                short8 b = WFRAG(Wout2t, 256, n0, kk);
                MFMA(acc, a, b);
            }
            const int col = n0 + cl;
            #pragma unroll
            for (int i = 0; i < 4; ++i) {
                int r = wr0 + kg * 4 + i;
                long t = t0 + r;
                Out[t * 128 + col] = sA[r * 132 + col] + g2s[nt * 4 + i] * acc[i];
            }
        }
    }
}

// ---------------------------------------------------------------------------
extern "C" void kernel_launch(void* const* d_in, const int* in_sizes, int n_in,
                              void* d_out, int out_size, void* d_ws, size_t ws_size,
                              hipStream_t stream)
{
    const float* A_I  = (const float*)d_in[0];
    const float* S_I  = (const float*)d_in[1];
    const float* Z    = (const float*)d_in[2];
    const float* maskK = (const float*)d_in[6];
    const float* a1Wg = (const float*)d_in[7];
    const float* a1bg = (const float*)d_in[8];
    const float* a1Ws = (const float*)d_in[9];
    const float* Wq   = (const float*)d_in[10];
    const float* bq   = (const float*)d_in[11];
    const float* Wk   = (const float*)d_in[12];
    const float* Wv   = (const float*)d_in[13];
    const float* ln0g = (const float*)d_in[14];
    const float* ln0b = (const float*)d_in[15];
    const float* Wb   = (const float*)d_in[16];
    const float* Wga  = (const float*)d_in[17];
    const float* Wa   = (const float*)d_in[18];
    const float* Wop  = (const float*)d_in[19];
    const float* bop  = (const float*)d_in[20];
    const float* a2Wg = (const float*)d_in[21];
    const float* a2bg = (const float*)d_in[22];
    const float* a2Ws = (const float*)d_in[23];
    const float* Wsw  = (const float*)d_in[24];
    const float* Wlin = (const float*)d_in[25];
    const float* ctWg = (const float*)d_in[26];
    const float* ctbg = (const float*)d_in[27];
    const float* Wout2 = (const float*)d_in[28];
    float* out = (float*)d_out;

    const size_t NTC = (size_t)DL * 128;   // 2,097,152 elems per (D,L,C) tensor
    short* Qb = (short*)d_ws;
    short* Kb = Qb + NTC;
    short* Vb = Kb + NTC;
    short* Gb = Vb + NTC;
    float* BB = (float*)(Gb + NTC);        // [64][4][32][128] f32 = 4 MB
    short* wbt = (short*)(BB + (size_t)NQB * 4 * 32 * 128);
    short* AFb = Qb;   // attention output aliases Qb (per-element RAW within block, barrier-separated)

    short* Wg1t = wbt + 0 * 16384;
    short* Ws1t = wbt + 1 * 16384;
    short* Wqt  = wbt + 2 * 16384;
    short* Wkt  = wbt + 3 * 16384;
    short* Wvt  = wbt + 4 * 16384;
    short* Wgat = wbt + 5 * 16384;
    short* Wat  = wbt + 6 * 16384;
    short* Wopt = wbt + 7 * 16384;
    short* ctWgt = wbt + 8 * 16384;
    short* Wg2t = wbt + 9 * 16384;
    short* Ws2t = wbt + 10 * 16384;
    short* Wswt = wbt + 180224;
    short* Wlint = wbt + 212992;
    short* Wout2t = wbt + 245760;

    k_wprep<<<1088, 256, 0, stream>>>(a1Wg, a1Ws, Wq, Wk, Wv, Wga, Wa, Wop, ctWg,
                                      a2Wg, a2Ws, Wsw, Wlin, Wout2, wbt);
    k_adaln_qkvg<<<DL / 64, 256, 0, stream>>>(A_I, S_I, Wg1t, Ws1t, Wqt, Wkt, Wvt, Wgat,
                                              a1bg, bq, Qb, Kb, Vb, Gb);
    k_bias<<<NQB * 4, 256, 0, stream>>>(Z, ln0g, ln0b, Wb, BB);
    k_attn<<<dim3(NQB, 4, 8), 256, 0, stream>>>(Qb, Kb, Vb, Gb, BB, maskK, AFb);
    k_postf<<<DL / 64, 256, 0, stream>>>(AFb, S_I, A_I, Wat, Wopt, ctWgt, Wg2t, Ws2t,
                                         Wswt, Wlint, Wout2t, bop, ctbg, a2bg, out);
}

// Round 4
// 114.545 us; speedup vs baseline: 2.5412x; 1.0069x over previous
//
#include <hip/hip_runtime.h>

// Problem constants
#define DL 16384   // D*L tokens
#define LL 2048
#define NQB 64     // NQ
#define QBS 32     // QB
#define KBS 128    // KB

typedef __attribute__((ext_vector_type(8))) short short8;
typedef __attribute__((ext_vector_type(4))) short short4v;
typedef __attribute__((ext_vector_type(4))) float f32x4;

__device__ __forceinline__ float sigmoidf_(float x) { return 1.f / (1.f + expf(-x)); }

__device__ __forceinline__ short f2bf(float f) {
    union { float f; unsigned u; } v; v.f = f;
    unsigned r = (v.u + 0x7FFFu + ((v.u >> 16) & 1u)) >> 16;
    return (short)r;
}
__device__ __forceinline__ float bf2f(short h) {
    union { unsigned u; float f; } v; v.u = ((unsigned)(unsigned short)h) << 16;
    return v.f;
}

// fragment helpers (cl = lane&15, kg = lane>>4 must be in scope)
#define AFRAG(buf, stride, r0, kk) (*(const short8*)&(buf)[(size_t)((r0) + cl) * (stride) + (kk) * 32 + kg * 8])
#define WFRAG(Wt, K, n0, kk) (*(const short8*)((Wt) + (size_t)((n0) + cl) * (K) + (kk) * 32 + kg * 8))
#define MFMA(acc, a, b) acc = __builtin_amdgcn_mfma_f32_16x16x32_bf16(a, b, acc, 0, 0, 0)

// ---------------------------------------------------------------------------
// Kernel 0: fused prep.
//   blocks 0..16 : weight transpose to bf16 [N][K] via LDS tile (coalesced both sides)
//   blocks 17..272: pair-bias  BBt[n][h][j][i] bf16 = ((LN(Z[q,kc,:])*g+b) @ Wb)[h]
// ---------------------------------------------------------------------------
__global__ __launch_bounds__(256) void k_prep(
    const float* __restrict__ W0, const float* __restrict__ W1, const float* __restrict__ W2,
    const float* __restrict__ W3, const float* __restrict__ W4, const float* __restrict__ W5,
    const float* __restrict__ W6, const float* __restrict__ W7, const float* __restrict__ W8,
    const float* __restrict__ W9, const float* __restrict__ W10,
    const float* __restrict__ Wsw, const float* __restrict__ Wlin, const float* __restrict__ Wout2,
    const float* __restrict__ Z, const float* __restrict__ g16, const float* __restrict__ b16,
    const float* __restrict__ Wb,
    short* __restrict__ wout, short* __restrict__ BBt)
{
    __shared__ float sW[128 * 128];          // 64 KB (weight-transpose path)
    __shared__ float sWb[64], sg[16], sb[16];
    __shared__ short sT[4 * 8 * 128];        // bias path staging
    const int b = blockIdx.x;
    const int tid = threadIdx.x;

    if (b < 17) {
        const float* srcs[14] = {W0,W1,W2,W3,W4,W5,W6,W7,W8,W9,W10,Wsw,Wlin,Wout2};
        const int sel[17]  = {0,1,2,3,4,5,6,7,8,9,10,11,11,12,12,13,13};
        const int soff[17] = {0,0,0,0,0,0,0,0,0,0,0, 0,128, 0,128, 0,16384};
        const int sN[17]   = {128,128,128,128,128,128,128,128,128,128,128, 256,256,256,256, 128,128};
        const int doff[17] = {0,16384,32768,49152,65536,81920,98304,114688,131072,147456,163840,
                              180224,196608, 212992,229376, 245760,245888};
        const int dK[17]   = {128,128,128,128,128,128,128,128,128,128,128, 128,128,128,128, 256,256};
        const float* src = srcs[sel[b]] + soff[b];
        const int srcN = sN[b];
        short* dst = wout + doff[b];
        const int dstK = dK[b];
        {   // coalesced load of 128x128 f32 tile
            const int r = tid >> 1, ch = (tid & 1) * 64;
            #pragma unroll
            for (int u = 0; u < 16; ++u) {
                float4 v = *(const float4*)(src + (size_t)r * srcN + ch + u * 4);
                *(float4*)&sW[r * 128 + ch + u * 4] = v;
            }
        }
        __syncthreads();
        {   // coalesced transposed bf16 write
            const int o = tid >> 1, kh = (tid & 1) * 64;
            #pragma unroll
            for (int u8 = 0; u8 < 8; ++u8) {
                short8 pk;
                #pragma unroll
                for (int e = 0; e < 8; ++e)
                    pk[e] = f2bf(sW[(kh + u8 * 8 + e) * 128 + o]);
                *(short8*)(dst + (size_t)o * dstK + kh + u8 * 8) = pk;
            }
        }
    } else {
        const int bb = b - 17;
        const int n = bb >> 2;
        const int io = (bb & 3) * 8;
        if (tid < 64) sWb[tid] = Wb[tid];
        if (tid < 16) { sg[tid] = g16[tid]; sb[tid] = b16[tid]; }
        __syncthreads();
        for (int p = 0; p < 4; ++p) {
            int pair = tid + 256 * p;        // 8*128 pairs
            int il = pair >> 7, j = pair & 127;
            int i = io + il;
            int kr = n * 32 - 48 + j;
            int kc = min(max(kr, 0), LL - 1);
            const float4* z4 = (const float4*)(Z + ((long)(n * 32 + i) * LL + kc) * 16);
            float zv[16];
            #pragma unroll
            for (int w = 0; w < 4; ++w) {
                float4 v = z4[w];
                zv[w * 4 + 0] = v.x; zv[w * 4 + 1] = v.y; zv[w * 4 + 2] = v.z; zv[w * 4 + 3] = v.w;
            }
            float sm = 0.f, sq = 0.f;
            #pragma unroll
            for (int cp = 0; cp < 16; ++cp) { sm += zv[cp]; sq = fmaf(zv[cp], zv[cp], sq); }
            float m = sm * (1.f / 16.f);
            float rs = rsqrtf(sq * (1.f / 16.f) - m * m + 1e-5f);
            float b0 = 0.f, b1 = 0.f, b2 = 0.f, b3 = 0.f;
            #pragma unroll
            for (int cp = 0; cp < 16; ++cp) {
                float zn = (zv[cp] - m) * rs * sg[cp] + sb[cp];
                b0 = fmaf(zn, sWb[cp * 4 + 0], b0);
                b1 = fmaf(zn, sWb[cp * 4 + 1], b1);
                b2 = fmaf(zn, sWb[cp * 4 + 2], b2);
                b3 = fmaf(zn, sWb[cp * 4 + 3], b3);
            }
            sT[(0 * 8 + il) * 128 + j] = f2bf(b0);
            sT[(1 * 8 + il) * 128 + j] = f2bf(b1);
            sT[(2 * 8 + il) * 128 + j] = f2bf(b2);
            sT[(3 * 8 + il) * 128 + j] = f2bf(b3);
        }
        __syncthreads();
        #pragma unroll
        for (int rr = 0; rr < 2; ++rr) {
            int cid = tid + rr * 256;
            int hh = cid >> 7, j = cid & 127;
            short8 pk;
            #pragma unroll
            for (int e = 0; e < 8; ++e) pk[e] = sT[(hh * 8 + e) * 128 + j];
            *(short8*)(BBt + (((size_t)n * 4 + hh) * 128 + j) * 32 + io) = pk;
        }
    }
}

// ---------------------------------------------------------------------------
// Kernel 1: adaLN1 + QKV+G projections via MFMA.  64 tokens / block.
// Outputs bf16: Q pre-scaled by 1/sqrt(32), K, V, G=sigmoid(.)
// ---------------------------------------------------------------------------
__global__ __launch_bounds__(256) void k_adaln_qkvg(
    const float* __restrict__ A_I, const float* __restrict__ S_I,
    const short* __restrict__ Wg1t, const short* __restrict__ Ws1t,
    const short* __restrict__ Wqt, const short* __restrict__ Wkt,
    const short* __restrict__ Wvt, const short* __restrict__ Wgat,
    const float* __restrict__ bg1, const float* __restrict__ bq,
    short* __restrict__ Qo, short* __restrict__ Ko, short* __restrict__ Vo, short* __restrict__ Go)
{
    __shared__ short sAr[64 * 136];   // raw A bf16
    __shared__ short sSn[64 * 136];   // LN(S) bf16
    __shared__ short sAn[64 * 136];   // An bf16
    __shared__ float sMean[64], sRstd[64];
    const int tid = threadIdx.x;
    const int lane = tid & 63;
    const long t0 = (long)blockIdx.x * 64;

    {   // P0: load A,S; LN stats; stage bf16
        const int row = tid >> 2, seg = tid & 3;
        const float* ap = A_I + (t0 + row) * 128 + seg * 32;
        const float* sp = S_I + (t0 + row) * 128 + seg * 32;
        float av[32], sv[32];
        #pragma unroll
        for (int u = 0; u < 8; ++u) {
            float4 a4 = ((const float4*)ap)[u];
            float4 s4 = ((const float4*)sp)[u];
            av[4*u] = a4.x; av[4*u+1] = a4.y; av[4*u+2] = a4.z; av[4*u+3] = a4.w;
            sv[4*u] = s4.x; sv[4*u+1] = s4.y; sv[4*u+2] = s4.z; sv[4*u+3] = s4.w;
        }
        float am = 0.f, aq = 0.f, sm = 0.f, sq = 0.f;
        #pragma unroll
        for (int u = 0; u < 32; ++u) {
            am += av[u]; aq = fmaf(av[u], av[u], aq);
            sm += sv[u]; sq = fmaf(sv[u], sv[u], sq);
        }
        am += __shfl_xor(am, 1); am += __shfl_xor(am, 2);
        aq += __shfl_xor(aq, 1); aq += __shfl_xor(aq, 2);
        sm += __shfl_xor(sm, 1); sm += __shfl_xor(sm, 2);
        sq += __shfl_xor(sq, 1); sq += __shfl_xor(sq, 2);
        float amean = am * (1.f / 128.f);
        float arstd = rsqrtf(aq * (1.f / 128.f) - amean * amean + 1e-5f);
        float smean = sm * (1.f / 128.f);
        float srstd = rsqrtf(sq * (1.f / 128.f) - smean * smean + 1e-5f);
        if ((tid & 3) == 0) { sMean[row] = amean; sRstd[row] = arstd; }
        #pragma unroll
        for (int g = 0; g < 4; ++g) {
            short8 pa, ps;
            #pragma unroll
            for (int e = 0; e < 8; ++e) {
                pa[e] = f2bf(av[g * 8 + e]);
                ps[e] = f2bf((sv[g * 8 + e] - smean) * srstd);
            }
            *(short8*)&sAr[row * 136 + seg * 32 + g * 8] = pa;
            *(short8*)&sSn[row * 136 + seg * 32 + g * 8] = ps;
        }
    }
    __syncthreads();
    const int w = tid >> 6, wr0 = w * 16;
    const int cl = lane & 15, kg = lane >> 4;
    {   // P1: An = sigmoid(sn@Wg1+bg1)*an + sn@Ws1
        for (int nt = 0; nt < 8; ++nt) {
            f32x4 ag = {0.f, 0.f, 0.f, 0.f}, as = {0.f, 0.f, 0.f, 0.f};
            const int n0 = nt * 16;
            #pragma unroll
            for (int kk = 0; kk < 4; ++kk) {
                short8 a = AFRAG(sSn, 136, wr0, kk);
                short8 bg = WFRAG(Wg1t, 128, n0, kk);
                short8 bs = WFRAG(Ws1t, 128, n0, kk);
                MFMA(ag, a, bg);
                MFMA(as, a, bs);
            }
            const int col = n0 + cl;
            float bgc = bg1[col];
            #pragma unroll
            for (int i = 0; i < 4; ++i) {
                int r = wr0 + kg * 4 + i;
                float an = (bf2f(sAr[r * 136 + col]) - sMean[r]) * sRstd[r];
                float An = sigmoidf_(ag[i] + bgc) * an + as[i];
                sAn[r * 136 + col] = f2bf(An);
            }
        }
    }
    __syncthreads();
    {   // P2: Q,K,V,G = An @ {Wq,Wk,Wv,Wga}  (bf16 stores)
        const float SCL = 0.17677669529663687f;  // 1/sqrt(32)
        for (int nt = 0; nt < 32; ++nt) {
            const short* Wt = (nt < 8) ? Wqt : (nt < 16) ? Wkt : (nt < 24) ? Wvt : Wgat;
            const int n0 = (nt & 7) * 16;
            f32x4 acc = {0.f, 0.f, 0.f, 0.f};
            #pragma unroll
            for (int kk = 0; kk < 4; ++kk) {
                short8 a = AFRAG(sAn, 136, wr0, kk);
                short8 b = WFRAG(Wt, 128, n0, kk);
                MFMA(acc, a, b);
            }
            const int col = n0 + cl;
            #pragma unroll
            for (int i = 0; i < 4; ++i) {
                long t = t0 + wr0 + kg * 4 + i;
                float v = acc[i];
                if (nt < 8)       Qo[t * 128 + col] = f2bf((v + bq[col]) * SCL);
                else if (nt < 16) Ko[t * 128 + col] = f2bf(v);
                else if (nt < 24) Vo[t * 128 + col] = f2bf(v);
                else              Go[t * 128 + col] = f2bf(sigmoidf_(v));
            }
        }
    }
}

// ---------------------------------------------------------------------------
// Kernel 3: windowed attention, block = (n,d), wave = head.
// Q/K fragments straight from global; scores in registers; V^T + P in LDS.
// ---------------------------------------------------------------------------
__global__ __launch_bounds__(256) void k_attn(
    const short* __restrict__ Qg, const short* __restrict__ Kg, const short* __restrict__ Vg,
    const short* __restrict__ Gg, const short* __restrict__ BBt, const float* __restrict__ maskK,
    short* __restrict__ AFo)
{
    __shared__ short vts[4 * 32 * 136];   // per-head V^T [c][key]
    __shared__ short Pl [4 * 32 * 136];   // per-head P [q][key]
    const int n = blockIdx.x, d = blockIdx.y;
    const int tid = threadIdx.x;
    const int lane = tid & 63;
    const int h = tid >> 6;
    const long tb = (long)d * LL;
    const int kbase = n * 32 - 48;
    short* vtsH = vts + h * 4352;
    short* PH   = Pl  + h * 4352;
    const int cl = lane & 15, kg = lane >> 4;

    {   // V transpose: lane handles keys 2*lane, 2*lane+1, channels 0..31 of head h
        const int j0 = lane * 2;
        int kc0 = min(max(kbase + j0, 0), LL - 1);
        int kc1 = min(max(kbase + j0 + 1, 0), LL - 1);
        const short8* p0 = (const short8*)(Vg + (tb + kc0) * 128 + h * 32);
        const short8* p1 = (const short8*)(Vg + (tb + kc1) * 128 + h * 32);
        short8 ev[4] = {p0[0], p0[1], p0[2], p0[3]};
        short8 ov[4] = {p1[0], p1[1], p1[2], p1[3]};
        #pragma unroll
        for (int g = 0; g < 4; ++g)
            #pragma unroll
            for (int e = 0; e < 8; ++e)
                *(unsigned*)&vtsH[(g * 8 + e) * 136 + j0] =
                    (unsigned)(unsigned short)ev[g][e] | ((unsigned)(unsigned short)ov[g][e] << 16);
    }
    __syncthreads();

    float sc[2][8][4];
    {   // QK^T straight from global + bias + mask
        short8 qf[2];
        #pragma unroll
        for (int mt = 0; mt < 2; ++mt)
            qf[mt] = *(const short8*)(Qg + (tb + n * 32 + mt * 16 + cl) * 128 + h * 32 + kg * 8);
        #pragma unroll
        for (int nt = 0; nt < 8; ++nt) {
            const int key = nt * 16 + cl;
            int kc = min(max(kbase + key, 0), LL - 1);
            short8 kf = *(const short8*)(Kg + (tb + kc) * 128 + h * 32 + kg * 8);
            float mk = maskK[n * 128 + key] * 1e9f;
            #pragma unroll
            for (int mt = 0; mt < 2; ++mt) {
                f32x4 s = {0.f, 0.f, 0.f, 0.f};
                MFMA(s, qf[mt], kf);
                short4v bfr = *(const short4v*)(BBt + (((size_t)n * 4 + h) * 128 + key) * 32 + mt * 16 + kg * 4);
                #pragma unroll
                for (int i = 0; i < 4; ++i)
                    sc[mt][nt][i] = s[i] + bf2f(bfr[i]) - mk;
            }
        }
    }
    {   // in-register softmax per q-row (16-lane cl-group holds the 128 keys)
        #pragma unroll
        for (int mt = 0; mt < 2; ++mt) {
            #pragma unroll
            for (int i = 0; i < 4; ++i) {
                float mx = sc[mt][0][i];
                #pragma unroll
                for (int nt = 1; nt < 8; ++nt) mx = fmaxf(mx, sc[mt][nt][i]);
                mx = fmaxf(mx, __shfl_xor(mx, 1));
                mx = fmaxf(mx, __shfl_xor(mx, 2));
                mx = fmaxf(mx, __shfl_xor(mx, 4));
                mx = fmaxf(mx, __shfl_xor(mx, 8));
                float sm = 0.f;
                #pragma unroll
                for (int nt = 0; nt < 8; ++nt) {
                    float p = __expf(sc[mt][nt][i] - mx);
                    sc[mt][nt][i] = p; sm += p;
                }
                sm += __shfl_xor(sm, 1);
                sm += __shfl_xor(sm, 2);
                sm += __shfl_xor(sm, 4);
                sm += __shfl_xor(sm, 8);
                float inv = 1.f / sm;
                const int q = mt * 16 + kg * 4 + i;
                #pragma unroll
                for (int nt = 0; nt < 8; ++nt)
                    PH[q * 136 + nt * 16 + cl] = f2bf(sc[mt][nt][i] * inv);
            }
        }
    }
    __syncthreads();
    {   // PV + G-gate + store
        #pragma unroll
        for (int mt = 0; mt < 2; ++mt) {
            #pragma unroll
            for (int ct = 0; ct < 2; ++ct) {
                f32x4 acc = {0.f, 0.f, 0.f, 0.f};
                #pragma unroll
                for (int kk = 0; kk < 4; ++kk) {
                    short8 a = *(const short8*)&PH[(mt * 16 + cl) * 136 + kk * 32 + kg * 8];
                    short8 b = *(const short8*)&vtsH[(ct * 16 + cl) * 136 + kk * 32 + kg * 8];
                    MFMA(acc, a, b);
                }
                const int col = h * 32 + ct * 16 + cl;
                #pragma unroll
                for (int i = 0; i < 4; ++i) {
                    long t = tb + n * 32 + mt * 16 + kg * 4 + i;
                    float g = bf2f(Gg[t * 128 + col]);
                    AFo[t * 128 + col] = f2bf(g * acc[i]);
                }
            }
        }
    }
}

// ---------------------------------------------------------------------------
// Kernel 4: fused post: af@Wa gate residual + adaLN2 + SwiGLU + ct-gate.
// 64 tokens / block, MFMA everywhere.  AF input is bf16.
// ---------------------------------------------------------------------------
__global__ __launch_bounds__(256) void k_postf(
    const short* __restrict__ AF, const float* __restrict__ S_I, const float* __restrict__ A_I,
    const short* __restrict__ Wat, const short* __restrict__ Wopt, const short* __restrict__ ctWgt,
    const short* __restrict__ Wg2t, const short* __restrict__ Ws2t,
    const short* __restrict__ Wswt, const short* __restrict__ Wlint, const short* __restrict__ Wout2t,
    const float* __restrict__ bop, const float* __restrict__ ctbg, const float* __restrict__ bg2,
    float* __restrict__ Out)
{
    __shared__ __align__(16) char smem[86528];
    short* sAF  = (short*)smem;              // [64][136] bf16 AF       -> reused as sAn2
    short* sS   = (short*)(smem + 17408);    // [64][136] bf16 raw S    -> reused by sB
    short* sSn  = (short*)(smem + 34816);    // [64][136] bf16 LN(S)    (partly reused by sB)
    float* sA   = (float*)(smem + 52224);    // [64][132] f32 A (raw, kept)
    float* sMean = (float*)(smem + 86016);   // [64]
    float* sRstd = (float*)(smem + 86272);   // [64]
    short* sAn2 = sAF;                       // [64][136] bf16 an2
    short* sB   = (short*)(smem + 17408);    // [64][264] bf16 b

    const int tid = threadIdx.x;
    const int lane = tid & 63;
    const long t0 = (long)blockIdx.x * 64;

    {   // P0: copy AF (bf16) ; load S -> raw bf16 + LN bf16
        const int row = tid >> 2, seg = tid & 3;
        const short8* fp = (const short8*)(AF + (t0 + row) * 128 + seg * 32);
        #pragma unroll
        for (int g = 0; g < 4; ++g)
            *(short8*)&sAF[row * 136 + seg * 32 + g * 8] = fp[g];
        const float* sp = S_I + (t0 + row) * 128 + seg * 32;
        float sv[32];
        #pragma unroll
        for (int u = 0; u < 8; ++u) {
            float4 s4 = ((const float4*)sp)[u];
            sv[4*u] = s4.x; sv[4*u+1] = s4.y; sv[4*u+2] = s4.z; sv[4*u+3] = s4.w;
        }
        float sm = 0.f, sq = 0.f;
        #pragma unroll
        for (int u = 0; u < 32; ++u) { sm += sv[u]; sq = fmaf(sv[u], sv[u], sq); }
        sm += __shfl_xor(sm, 1); sm += __shfl_xor(sm, 2);
        sq += __shfl_xor(sq, 1); sq += __shfl_xor(sq, 2);
        float smean = sm * (1.f / 128.f);
        float srstd = rsqrtf(sq * (1.f / 128.f) - smean * smean + 1e-5f);
        #pragma unroll
        for (int g = 0; g < 4; ++g) {
            short8 pr, pn;
            #pragma unroll
            for (int e = 0; e < 8; ++e) {
                float s = sv[g * 8 + e];
                pr[e] = f2bf(s);
                pn[e] = f2bf((s - smean) * srstd);
            }
            *(short8*)&sS [row * 136 + seg * 32 + g * 8] = pr;
            *(short8*)&sSn[row * 136 + seg * 32 + g * 8] = pn;
        }
    }
    __syncthreads();
    const int w = tid >> 6, wr0 = w * 16;
    const int cl = lane & 15, kg = lane >> 4;
    float g2s[32];   // ct gate, persists to P6 (loops fully unrolled -> registers)

    {   // P2: A = A_I + sigmoid(S@Wop+bop) * (AF@Wa);  g2 = sigmoid(S@ctWg+ctbg)
        #pragma unroll
        for (int nt = 0; nt < 8; ++nt) {
            f32x4 aA = {0.f,0.f,0.f,0.f}, aO = {0.f,0.f,0.f,0.f}, aG = {0.f,0.f,0.f,0.f};
            const int n0 = nt * 16;
            #pragma unroll
            for (int kk = 0; kk < 4; ++kk) {
                short8 af = AFRAG(sAF, 136, wr0, kk);
                short8 sf = AFRAG(sS, 136, wr0, kk);
                short8 bA = WFRAG(Wat, 128, n0, kk);
                short8 bO = WFRAG(Wopt, 128, n0, kk);
                short8 bG = WFRAG(ctWgt, 128, n0, kk);
                MFMA(aA, af, bA);
                MFMA(aO, sf, bO);
                MFMA(aG, sf, bG);
            }
            const int col = n0 + cl;
            float bopc = bop[col], ctc = ctbg[col];
            #pragma unroll
            for (int i = 0; i < 4; ++i) {
                int r = wr0 + kg * 4 + i;
                long t = t0 + r;
                float Aval = A_I[t * 128 + col] + sigmoidf_(aO[i] + bopc) * aA[i];
                sA[r * 132 + col] = Aval;
                g2s[nt * 4 + i] = sigmoidf_(aG[i] + ctc);
            }
        }
    }
    __syncthreads();
    {   // P3: LN stats of A rows
        const int row = tid >> 2, seg = tid & 3;
        float m = 0.f, q = 0.f;
        #pragma unroll
        for (int u = 0; u < 8; ++u) {
            float4 v = *(const float4*)&sA[row * 132 + seg * 32 + u * 4];
            m += v.x + v.y + v.z + v.w;
            q = fmaf(v.x, v.x, q); q = fmaf(v.y, v.y, q);
            q = fmaf(v.z, v.z, q); q = fmaf(v.w, v.w, q);
        }
        m += __shfl_xor(m, 1); m += __shfl_xor(m, 2);
        q += __shfl_xor(q, 1); q += __shfl_xor(q, 2);
        float mean = m * (1.f / 128.f);
        float rstd = rsqrtf(q * (1.f / 128.f) - mean * mean + 1e-5f);
        if ((tid & 3) == 0) { sMean[row] = mean; sRstd[row] = rstd; }
    }
    __syncthreads();
    {   // P4: an2 = sigmoid(sn@Wg2+bg2)*LN(A) + sn@Ws2  (writes sAn2 = old sAF)
        for (int nt = 0; nt < 8; ++nt) {
            f32x4 ag = {0.f,0.f,0.f,0.f}, as = {0.f,0.f,0.f,0.f};
            const int n0 = nt * 16;
            #pragma unroll
            for (int kk = 0; kk < 4; ++kk) {
                short8 a = AFRAG(sSn, 136, wr0, kk);
                short8 bg = WFRAG(Wg2t, 128, n0, kk);
                short8 bs = WFRAG(Ws2t, 128, n0, kk);
                MFMA(ag, a, bg);
                MFMA(as, a, bs);
            }
            const int col = n0 + cl;
            float bg2c = bg2[col];
            #pragma unroll
            for (int i = 0; i < 4; ++i) {
                int r = wr0 + kg * 4 + i;
                float lnA = (sA[r * 132 + col] - sMean[r]) * sRstd[r];
                sAn2[r * 136 + col] = f2bf(sigmoidf_(ag[i] + bg2c) * lnA + as[i]);
            }
        }
    }
    __syncthreads();
    {   // P5: b = silu(an2@Wsw) * (an2@Wlin)   (writes sB over sS/sSn region)
        for (int nt = 0; nt < 16; ++nt) {
            f32x4 aw = {0.f,0.f,0.f,0.f}, al = {0.f,0.f,0.f,0.f};
            const int n0 = nt * 16;
            #pragma unroll
            for (int kk = 0; kk < 4; ++kk) {
                short8 a = AFRAG(sAn2, 136, wr0, kk);
                short8 bw = WFRAG(Wswt, 128, n0, kk);
                short8 bl = WFRAG(Wlint, 128, n0, kk);
                MFMA(aw, a, bw);
                MFMA(al, a, bl);
            }
            const int col2 = n0 + cl;
            #pragma unroll
            for (int i = 0; i < 4; ++i) {
                int r = wr0 + kg * 4 + i;
                float x = aw[i];
                float bb = (x / (1.f + expf(-x))) * al[i];
                sB[r * 264 + col2] = f2bf(bb);
            }
        }
    }
    __syncthreads();
    {   // P6: out = A + g2 * (b @ Wout2)
        #pragma unroll
        for (int nt = 0; nt < 8; ++nt) {
            f32x4 acc = {0.f,0.f,0.f,0.f};
            const int n0 = nt * 16;
            #pragma unroll
            for (int kk = 0; kk < 8; ++kk) {
                short8 a = AFRAG(sB, 264, wr0, kk);
                short8 b = WFRAG(Wout2t, 256, n0, kk);
                MFMA(acc, a, b);
            }
            const int col = n0 + cl;
            #pragma unroll
            for (int i = 0; i < 4; ++i) {
                int r = wr0 + kg * 4 + i;
                long t = t0 + r;
                Out[t * 128 + col] = sA[r * 132 + col] + g2s[nt * 4 + i] * acc[i];
            }
        }
    }
}

// ---------------------------------------------------------------------------
extern "C" void kernel_launch(void* const* d_in, const int* in_sizes, int n_in,
                              void* d_out, int out_size, void* d_ws, size_t ws_size,
                              hipStream_t stream)
{
    const float* A_I  = (const float*)d_in[0];
    const float* S_I  = (const float*)d_in[1];
    const float* Z    = (const float*)d_in[2];
    const float* maskK = (const float*)d_in[6];
    const float* a1Wg = (const float*)d_in[7];
    const float* a1bg = (const float*)d_in[8];
    const float* a1Ws = (const float*)d_in[9];
    const float* Wq   = (const float*)d_in[10];
    const float* bq   = (const float*)d_in[11];
    const float* Wk   = (const float*)d_in[12];
    const float* Wv   = (const float*)d_in[13];
    const float* ln0g = (const float*)d_in[14];
    const float* ln0b = (const float*)d_in[15];
    const float* Wb   = (const float*)d_in[16];
    const float* Wga  = (const float*)d_in[17];
    const float* Wa   = (const float*)d_in[18];
    const float* Wop  = (const float*)d_in[19];
    const float* bop  = (const float*)d_in[20];
    const float* a2Wg = (const float*)d_in[21];
    const float* a2bg = (const float*)d_in[22];
    const float* a2Ws = (const float*)d_in[23];
    const float* Wsw  = (const float*)d_in[24];
    const float* Wlin = (const float*)d_in[25];
    const float* ctWg = (const float*)d_in[26];
    const float* ctbg = (const float*)d_in[27];
    const float* Wout2 = (const float*)d_in[28];
    float* out = (float*)d_out;

    const size_t NTC = (size_t)DL * 128;   // 2,097,152 elems per (D,L,C) tensor
    short* Qb = (short*)d_ws;
    short* Kb = Qb + NTC;
    short* Vb = Kb + NTC;
    short* Gb = Vb + NTC;
    short* BBt = Gb + NTC;                 // [64][4][128][32] bf16 = 2 MB
    short* wbt = BBt + (size_t)NQB * 4 * 128 * 32;
    short* AFb = Qb;   // attention output aliases Qb (block-local RAW, wave-ordered)

    short* Wg1t = wbt + 0 * 16384;
    short* Ws1t = wbt + 1 * 16384;
    short* Wqt  = wbt + 2 * 16384;
    short* Wkt  = wbt + 3 * 16384;
    short* Wvt  = wbt + 4 * 16384;
    short* Wgat = wbt + 5 * 16384;
    short* Wat  = wbt + 6 * 16384;
    short* Wopt = wbt + 7 * 16384;
    short* ctWgt = wbt + 8 * 16384;
    short* Wg2t = wbt + 9 * 16384;
    short* Ws2t = wbt + 10 * 16384;
    short* Wswt = wbt + 180224;
    short* Wlint = wbt + 212992;
    short* Wout2t = wbt + 245760;

    k_prep<<<273, 256, 0, stream>>>(a1Wg, a1Ws, Wq, Wk, Wv, Wga, Wa, Wop, ctWg,
                                    a2Wg, a2Ws, Wsw, Wlin, Wout2,
                                    Z, ln0g, ln0b, Wb, wbt, BBt);
    k_adaln_qkvg<<<DL / 64, 256, 0, stream>>>(A_I, S_I, Wg1t, Ws1t, Wqt, Wkt, Wvt, Wgat,
                                              a1bg, bq, Qb, Kb, Vb, Gb);
    k_attn<<<dim3(NQB, 8), 256, 0, stream>>>(Qb, Kb, Vb, Gb, BBt, maskK, AFb);
    k_postf<<<DL / 64, 256, 0, stream>>>(AFb, S_I, A_I, Wat, Wopt, ctWgt, Wg2t, Ws2t,
                                         Wswt, Wlint, Wout2t, bop, ctbg, a2bg, out);
}

// Round 5
// 106.705 us; speedup vs baseline: 2.7279x; 1.0735x over previous
//
#include <hip/hip_runtime.h>

// Problem constants
#define DL 16384   // D*L tokens
#define LL 2048
#define NQB 64     // NQ
#define QBS 32     // QB
#define KBS 128    // KB

typedef __attribute__((ext_vector_type(8))) short short8;
typedef __attribute__((ext_vector_type(4))) short short4v;
typedef __attribute__((ext_vector_type(4))) float f32x4;

__device__ __forceinline__ float sigmoidf_(float x) { return 1.f / (1.f + expf(-x)); }

__device__ __forceinline__ short f2bf(float f) {
    union { float f; unsigned u; } v; v.f = f;
    unsigned r = (v.u + 0x7FFFu + ((v.u >> 16) & 1u)) >> 16;
    return (short)r;
}
__device__ __forceinline__ float bf2f(short h) {
    union { unsigned u; float f; } v; v.u = ((unsigned)(unsigned short)h) << 16;
    return v.f;
}

// fragment helpers (cl = lane&15, kg = lane>>4 must be in scope)
#define AFRAG(buf, stride, r0, kk) (*(const short8*)&(buf)[(size_t)((r0) + cl) * (stride) + (kk) * 32 + kg * 8])
#define WFRAG(Wt, K, n0, kk) (*(const short8*)((Wt) + (size_t)((n0) + cl) * (K) + (kk) * 32 + kg * 8))
#define MFMA(acc, a, b) acc = __builtin_amdgcn_mfma_f32_16x16x32_bf16(a, b, acc, 0, 0, 0)

// ---------------------------------------------------------------------------
// Kernel 0: fused prep.
//   blocks 0..16 : weight transpose to bf16 [N][K] via LDS tile
//   blocks 17..272: pair-bias  BBt[n][h][j][i] bf16
// ---------------------------------------------------------------------------
__global__ __launch_bounds__(256) void k_prep(
    const float* __restrict__ W0, const float* __restrict__ W1, const float* __restrict__ W2,
    const float* __restrict__ W3, const float* __restrict__ W4, const float* __restrict__ W5,
    const float* __restrict__ W6, const float* __restrict__ W7, const float* __restrict__ W8,
    const float* __restrict__ W9, const float* __restrict__ W10,
    const float* __restrict__ Wsw, const float* __restrict__ Wlin, const float* __restrict__ Wout2,
    const float* __restrict__ Z, const float* __restrict__ g16, const float* __restrict__ b16,
    const float* __restrict__ Wb,
    short* __restrict__ wout, short* __restrict__ BBt)
{
    __shared__ float sW[128 * 128];          // 64 KB (weight-transpose path)
    __shared__ float sWb[64], sg[16], sb[16];
    __shared__ short sT[4 * 8 * 128];        // bias path staging
    const int b = blockIdx.x;
    const int tid = threadIdx.x;

    if (b < 17) {
        const float* srcs[14] = {W0,W1,W2,W3,W4,W5,W6,W7,W8,W9,W10,Wsw,Wlin,Wout2};
        const int sel[17]  = {0,1,2,3,4,5,6,7,8,9,10,11,11,12,12,13,13};
        const int soff[17] = {0,0,0,0,0,0,0,0,0,0,0, 0,128, 0,128, 0,16384};
        const int sN[17]   = {128,128,128,128,128,128,128,128,128,128,128, 256,256,256,256, 128,128};
        const int doff[17] = {0,16384,32768,49152,65536,81920,98304,114688,131072,147456,163840,
                              180224,196608, 212992,229376, 245760,245888};
        const int dK[17]   = {128,128,128,128,128,128,128,128,128,128,128, 128,128,128,128, 256,256};
        const float* src = srcs[sel[b]] + soff[b];
        const int srcN = sN[b];
        short* dst = wout + doff[b];
        const int dstK = dK[b];
        {   // coalesced load of 128x128 f32 tile
            const int r = tid >> 1, ch = (tid & 1) * 64;
            #pragma unroll
            for (int u = 0; u < 16; ++u) {
                float4 v = *(const float4*)(src + (size_t)r * srcN + ch + u * 4);
                *(float4*)&sW[r * 128 + ch + u * 4] = v;
            }
        }
        __syncthreads();
        {   // coalesced transposed bf16 write
            const int o = tid >> 1, kh = (tid & 1) * 64;
            #pragma unroll
            for (int u8 = 0; u8 < 8; ++u8) {
                short8 pk;
                #pragma unroll
                for (int e = 0; e < 8; ++e)
                    pk[e] = f2bf(sW[(kh + u8 * 8 + e) * 128 + o]);
                *(short8*)(dst + (size_t)o * dstK + kh + u8 * 8) = pk;
            }
        }
    } else {
        const int bb = b - 17;
        const int n = bb >> 2;
        const int io = (bb & 3) * 8;
        if (tid < 64) sWb[tid] = Wb[tid];
        if (tid < 16) { sg[tid] = g16[tid]; sb[tid] = b16[tid]; }
        __syncthreads();
        for (int p = 0; p < 4; ++p) {
            int pair = tid + 256 * p;        // 8*128 pairs
            int il = pair >> 7, j = pair & 127;
            int i = io + il;
            int kr = n * 32 - 48 + j;
            int kc = min(max(kr, 0), LL - 1);
            const float4* z4 = (const float4*)(Z + ((long)(n * 32 + i) * LL + kc) * 16);
            float zv[16];
            #pragma unroll
            for (int w = 0; w < 4; ++w) {
                float4 v = z4[w];
                zv[w * 4 + 0] = v.x; zv[w * 4 + 1] = v.y; zv[w * 4 + 2] = v.z; zv[w * 4 + 3] = v.w;
            }
            float sm = 0.f, sq = 0.f;
            #pragma unroll
            for (int cp = 0; cp < 16; ++cp) { sm += zv[cp]; sq = fmaf(zv[cp], zv[cp], sq); }
            float m = sm * (1.f / 16.f);
            float rs = rsqrtf(sq * (1.f / 16.f) - m * m + 1e-5f);
            float b0 = 0.f, b1 = 0.f, b2 = 0.f, b3 = 0.f;
            #pragma unroll
            for (int cp = 0; cp < 16; ++cp) {
                float zn = (zv[cp] - m) * rs * sg[cp] + sb[cp];
                b0 = fmaf(zn, sWb[cp * 4 + 0], b0);
                b1 = fmaf(zn, sWb[cp * 4 + 1], b1);
                b2 = fmaf(zn, sWb[cp * 4 + 2], b2);
                b3 = fmaf(zn, sWb[cp * 4 + 3], b3);
            }
            sT[(0 * 8 + il) * 128 + j] = f2bf(b0);
            sT[(1 * 8 + il) * 128 + j] = f2bf(b1);
            sT[(2 * 8 + il) * 128 + j] = f2bf(b2);
            sT[(3 * 8 + il) * 128 + j] = f2bf(b3);
        }
        __syncthreads();
        #pragma unroll
        for (int rr = 0; rr < 2; ++rr) {
            int cid = tid + rr * 256;
            int hh = cid >> 7, j = cid & 127;
            short8 pk;
            #pragma unroll
            for (int e = 0; e < 8; ++e) pk[e] = sT[(hh * 8 + e) * 128 + j];
            *(short8*)(BBt + (((size_t)n * 4 + hh) * 128 + j) * 32 + io) = pk;
        }
    }
}

// ---------------------------------------------------------------------------
// Kernel 1: adaLN1 + QKV+G projections via MFMA.
// 64 tokens / block, 512 threads (8 waves): wave w -> rows (w&3)*16, col-half w>>2.
// ---------------------------------------------------------------------------
__global__ __launch_bounds__(512) void k_adaln_qkvg(
    const float* __restrict__ A_I, const float* __restrict__ S_I,
    const short* __restrict__ Wg1t, const short* __restrict__ Ws1t,
    const short* __restrict__ Wqt, const short* __restrict__ Wkt,
    const short* __restrict__ Wvt, const short* __restrict__ Wgat,
    const float* __restrict__ bg1, const float* __restrict__ bq,
    short* __restrict__ Qo, short* __restrict__ Ko, short* __restrict__ Vo, short* __restrict__ Go)
{
    __shared__ short sAr[64 * 136];   // raw A bf16
    __shared__ short sSn[64 * 136];   // LN(S) bf16
    __shared__ short sAn[64 * 136];   // An bf16
    __shared__ float sMean[64], sRstd[64];
    const int tid = threadIdx.x;
    const int lane = tid & 63;
    const long t0 = (long)blockIdx.x * 64;

    {   // P0: load A,S (16 f32 per thread); LN stats over 8-lane groups; stage bf16
        const int row = tid >> 3, seg = tid & 7;
        const float* ap = A_I + (t0 + row) * 128 + seg * 16;
        const float* sp = S_I + (t0 + row) * 128 + seg * 16;
        float av[16], sv[16];
        #pragma unroll
        for (int u = 0; u < 4; ++u) {
            float4 a4 = ((const float4*)ap)[u];
            float4 s4 = ((const float4*)sp)[u];
            av[4*u] = a4.x; av[4*u+1] = a4.y; av[4*u+2] = a4.z; av[4*u+3] = a4.w;
            sv[4*u] = s4.x; sv[4*u+1] = s4.y; sv[4*u+2] = s4.z; sv[4*u+3] = s4.w;
        }
        float am = 0.f, aq = 0.f, sm = 0.f, sq = 0.f;
        #pragma unroll
        for (int u = 0; u < 16; ++u) {
            am += av[u]; aq = fmaf(av[u], av[u], aq);
            sm += sv[u]; sq = fmaf(sv[u], sv[u], sq);
        }
        am += __shfl_xor(am, 1); am += __shfl_xor(am, 2); am += __shfl_xor(am, 4);
        aq += __shfl_xor(aq, 1); aq += __shfl_xor(aq, 2); aq += __shfl_xor(aq, 4);
        sm += __shfl_xor(sm, 1); sm += __shfl_xor(sm, 2); sm += __shfl_xor(sm, 4);
        sq += __shfl_xor(sq, 1); sq += __shfl_xor(sq, 2); sq += __shfl_xor(sq, 4);
        float amean = am * (1.f / 128.f);
        float arstd = rsqrtf(aq * (1.f / 128.f) - amean * amean + 1e-5f);
        float smean = sm * (1.f / 128.f);
        float srstd = rsqrtf(sq * (1.f / 128.f) - smean * smean + 1e-5f);
        if ((tid & 7) == 0) { sMean[row] = amean; sRstd[row] = arstd; }
        #pragma unroll
        for (int g = 0; g < 2; ++g) {
            short8 pa, ps;
            #pragma unroll
            for (int e = 0; e < 8; ++e) {
                pa[e] = f2bf(av[g * 8 + e]);
                ps[e] = f2bf((sv[g * 8 + e] - smean) * srstd);
            }
            *(short8*)&sAr[row * 136 + seg * 16 + g * 8] = pa;
            *(short8*)&sSn[row * 136 + seg * 16 + g * 8] = ps;
        }
    }
    __syncthreads();
    const int w = tid >> 6;
    const int wr0 = (w & 3) * 16;
    const int ch = w >> 2;            // column half (0 or 1)
    const int cl = lane & 15, kg = lane >> 4;
    {   // P1: An = sigmoid(sn@Wg1+bg1)*an + sn@Ws1 ; wave covers 4 col-tiles
        #pragma unroll
        for (int nt = 0; nt < 4; ++nt) {
            f32x4 ag = {0.f, 0.f, 0.f, 0.f}, as = {0.f, 0.f, 0.f, 0.f};
            const int n0 = ch * 64 + nt * 16;
            #pragma unroll
            for (int kk = 0; kk < 4; ++kk) {
                short8 a = AFRAG(sSn, 136, wr0, kk);
                short8 bg = WFRAG(Wg1t, 128, n0, kk);
                short8 bs = WFRAG(Ws1t, 128, n0, kk);
                MFMA(ag, a, bg);
                MFMA(as, a, bs);
            }
            const int col = n0 + cl;
            float bgc = bg1[col];
            #pragma unroll
            for (int i = 0; i < 4; ++i) {
                int r = wr0 + kg * 4 + i;
                float an = (bf2f(sAr[r * 136 + col]) - sMean[r]) * sRstd[r];
                float An = sigmoidf_(ag[i] + bgc) * an + as[i];
                sAn[r * 136 + col] = f2bf(An);
            }
        }
    }
    __syncthreads();
    {   // P2: Q,K,V,G = An @ {Wq,Wk,Wv,Wga}  (bf16 stores); 4 col-tiles per matrix
        const float SCL = 0.17677669529663687f;  // 1/sqrt(32)
        for (int m = 0; m < 4; ++m) {
            const short* Wt = (m == 0) ? Wqt : (m == 1) ? Wkt : (m == 2) ? Wvt : Wgat;
            #pragma unroll
            for (int nt = 0; nt < 4; ++nt) {
                const int n0 = ch * 64 + nt * 16;
                f32x4 acc = {0.f, 0.f, 0.f, 0.f};
                #pragma unroll
                for (int kk = 0; kk < 4; ++kk) {
                    short8 a = AFRAG(sAn, 136, wr0, kk);
                    short8 b = WFRAG(Wt, 128, n0, kk);
                    MFMA(acc, a, b);
                }
                const int col = n0 + cl;
                #pragma unroll
                for (int i = 0; i < 4; ++i) {
                    long t = t0 + wr0 + kg * 4 + i;
                    float v = acc[i];
                    if (m == 0)      Qo[t * 128 + col] = f2bf((v + bq[col]) * SCL);
                    else if (m == 1) Ko[t * 128 + col] = f2bf(v);
                    else if (m == 2) Vo[t * 128 + col] = f2bf(v);
                    else             Go[t * 128 + col] = f2bf(sigmoidf_(v));
                }
            }
        }
    }
}

// ---------------------------------------------------------------------------
// Kernel 3: windowed attention, block = (n,d), wave = head.
// Q/K fragments straight from global; scores in registers; V^T + P in LDS.
// ---------------------------------------------------------------------------
__global__ __launch_bounds__(256) void k_attn(
    const short* __restrict__ Qg, const short* __restrict__ Kg, const short* __restrict__ Vg,
    const short* __restrict__ Gg, const short* __restrict__ BBt, const float* __restrict__ maskK,
    short* __restrict__ AFo)
{
    __shared__ short vts[4 * 32 * 136];   // per-head V^T [c][key]
    __shared__ short Pl [4 * 32 * 136];   // per-head P [q][key]
    const int n = blockIdx.x, d = blockIdx.y;
    const int tid = threadIdx.x;
    const int lane = tid & 63;
    const int h = tid >> 6;
    const long tb = (long)d * LL;
    const int kbase = n * 32 - 48;
    short* vtsH = vts + h * 4352;
    short* PH   = Pl  + h * 4352;
    const int cl = lane & 15, kg = lane >> 4;

    {   // V transpose: lane handles keys 2*lane, 2*lane+1, channels 0..31 of head h
        const int j0 = lane * 2;
        int kc0 = min(max(kbase + j0, 0), LL - 1);
        int kc1 = min(max(kbase + j0 + 1, 0), LL - 1);
        const short8* p0 = (const short8*)(Vg + (tb + kc0) * 128 + h * 32);
        const short8* p1 = (const short8*)(Vg + (tb + kc1) * 128 + h * 32);
        short8 ev[4] = {p0[0], p0[1], p0[2], p0[3]};
        short8 ov[4] = {p1[0], p1[1], p1[2], p1[3]};
        #pragma unroll
        for (int g = 0; g < 4; ++g)
            #pragma unroll
            for (int e = 0; e < 8; ++e)
                *(unsigned*)&vtsH[(g * 8 + e) * 136 + j0] =
                    (unsigned)(unsigned short)ev[g][e] | ((unsigned)(unsigned short)ov[g][e] << 16);
    }
    __syncthreads();

    float sc[2][8][4];
    {   // QK^T straight from global + bias + mask
        short8 qf[2];
        #pragma unroll
        for (int mt = 0; mt < 2; ++mt)
            qf[mt] = *(const short8*)(Qg + (tb + n * 32 + mt * 16 + cl) * 128 + h * 32 + kg * 8);
        #pragma unroll
        for (int nt = 0; nt < 8; ++nt) {
            const int key = nt * 16 + cl;
            int kc = min(max(kbase + key, 0), LL - 1);
            short8 kf = *(const short8*)(Kg + (tb + kc) * 128 + h * 32 + kg * 8);
            float mk = maskK[n * 128 + key] * 1e9f;
            #pragma unroll
            for (int mt = 0; mt < 2; ++mt) {
                f32x4 s = {0.f, 0.f, 0.f, 0.f};
                MFMA(s, qf[mt], kf);
                short4v bfr = *(const short4v*)(BBt + (((size_t)n * 4 + h) * 128 + key) * 32 + mt * 16 + kg * 4);
                #pragma unroll
                for (int i = 0; i < 4; ++i)
                    sc[mt][nt][i] = s[i] + bf2f(bfr[i]) - mk;
            }
        }
    }
    {   // in-register softmax per q-row (16-lane cl-group holds the 128 keys)
        #pragma unroll
        for (int mt = 0; mt < 2; ++mt) {
            #pragma unroll
            for (int i = 0; i < 4; ++i) {
                float mx = sc[mt][0][i];
                #pragma unroll
                for (int nt = 1; nt < 8; ++nt) mx = fmaxf(mx, sc[mt][nt][i]);
                mx = fmaxf(mx, __shfl_xor(mx, 1));
                mx = fmaxf(mx, __shfl_xor(mx, 2));
                mx = fmaxf(mx, __shfl_xor(mx, 4));
                mx = fmaxf(mx, __shfl_xor(mx, 8));
                float sm = 0.f;
                #pragma unroll
                for (int nt = 0; nt < 8; ++nt) {
                    float p = __expf(sc[mt][nt][i] - mx);
                    sc[mt][nt][i] = p; sm += p;
                }
                sm += __shfl_xor(sm, 1);
                sm += __shfl_xor(sm, 2);
                sm += __shfl_xor(sm, 4);
                sm += __shfl_xor(sm, 8);
                float inv = 1.f / sm;
                const int q = mt * 16 + kg * 4 + i;
                #pragma unroll
                for (int nt = 0; nt < 8; ++nt)
                    PH[q * 136 + nt * 16 + cl] = f2bf(sc[mt][nt][i] * inv);
            }
        }
    }
    __syncthreads();
    {   // PV + G-gate + store
        #pragma unroll
        for (int mt = 0; mt < 2; ++mt) {
            #pragma unroll
            for (int ct = 0; ct < 2; ++ct) {
                f32x4 acc = {0.f, 0.f, 0.f, 0.f};
                #pragma unroll
                for (int kk = 0; kk < 4; ++kk) {
                    short8 a = *(const short8*)&PH[(mt * 16 + cl) * 136 + kk * 32 + kg * 8];
                    short8 b = *(const short8*)&vtsH[(ct * 16 + cl) * 136 + kk * 32 + kg * 8];
                    MFMA(acc, a, b);
                }
                const int col = h * 32 + ct * 16 + cl;
                #pragma unroll
                for (int i = 0; i < 4; ++i) {
                    long t = tb + n * 32 + mt * 16 + kg * 4 + i;
                    float g = bf2f(Gg[t * 128 + col]);
                    AFo[t * 128 + col] = f2bf(g * acc[i]);
                }
            }
        }
    }
}

// ---------------------------------------------------------------------------
// Kernel 4: fused post: af@Wa gate residual + adaLN2 + SwiGLU + ct-gate.
// 64 tokens / block, 512 threads (8 waves): wave w -> rows (w&3)*16, col-half w>>2.
// ---------------------------------------------------------------------------
__global__ __launch_bounds__(512) void k_postf(
    const short* __restrict__ AF, const float* __restrict__ S_I, const float* __restrict__ A_I,
    const short* __restrict__ Wat, const short* __restrict__ Wopt, const short* __restrict__ ctWgt,
    const short* __restrict__ Wg2t, const short* __restrict__ Ws2t,
    const short* __restrict__ Wswt, const short* __restrict__ Wlint, const short* __restrict__ Wout2t,
    const float* __restrict__ bop, const float* __restrict__ ctbg, const float* __restrict__ bg2,
    float* __restrict__ Out)
{
    __shared__ __align__(16) char smem[86528];
    short* sAF  = (short*)smem;              // [64][136] bf16 AF       -> reused as sAn2
    short* sS   = (short*)(smem + 17408);    // [64][136] bf16 raw S    -> reused by sB
    short* sSn  = (short*)(smem + 34816);    // [64][136] bf16 LN(S)    (partly reused by sB)
    float* sA   = (float*)(smem + 52224);    // [64][132] f32: raw A_I in P0, final A after P2
    float* sMean = (float*)(smem + 86016);   // [64]
    float* sRstd = (float*)(smem + 86272);   // [64]
    short* sAn2 = sAF;                       // [64][136] bf16 an2
    short* sB   = (short*)(smem + 17408);    // [64][264] bf16 b

    const int tid = threadIdx.x;
    const int lane = tid & 63;
    const long t0 = (long)blockIdx.x * 64;

    {   // P0: copy AF (bf16); load A_I -> sA f32; load S -> raw bf16 + LN bf16
        const int row = tid >> 3, seg = tid & 7;
        const short8* fp = (const short8*)(AF + (t0 + row) * 128 + seg * 16);
        #pragma unroll
        for (int g = 0; g < 2; ++g)
            *(short8*)&sAF[row * 136 + seg * 16 + g * 8] = fp[g];
        const float* apI = A_I + (t0 + row) * 128 + seg * 16;
        #pragma unroll
        for (int u = 0; u < 4; ++u)
            *(float4*)&sA[row * 132 + seg * 16 + u * 4] = ((const float4*)apI)[u];
        const float* sp = S_I + (t0 + row) * 128 + seg * 16;
        float sv[16];
        #pragma unroll
        for (int u = 0; u < 4; ++u) {
            float4 s4 = ((const float4*)sp)[u];
            sv[4*u] = s4.x; sv[4*u+1] = s4.y; sv[4*u+2] = s4.z; sv[4*u+3] = s4.w;
        }
        float sm = 0.f, sq = 0.f;
        #pragma unroll
        for (int u = 0; u < 16; ++u) { sm += sv[u]; sq = fmaf(sv[u], sv[u], sq); }
        sm += __shfl_xor(sm, 1); sm += __shfl_xor(sm, 2); sm += __shfl_xor(sm, 4);
        sq += __shfl_xor(sq, 1); sq += __shfl_xor(sq, 2); sq += __shfl_xor(sq, 4);
        float smean = sm * (1.f / 128.f);
        float srstd = rsqrtf(sq * (1.f / 128.f) - smean * smean + 1e-5f);
        #pragma unroll
        for (int g = 0; g < 2; ++g) {
            short8 pr, pn;
            #pragma unroll
            for (int e = 0; e < 8; ++e) {
                float s = sv[g * 8 + e];
                pr[e] = f2bf(s);
                pn[e] = f2bf((s - smean) * srstd);
            }
            *(short8*)&sS [row * 136 + seg * 16 + g * 8] = pr;
            *(short8*)&sSn[row * 136 + seg * 16 + g * 8] = pn;
        }
    }
    __syncthreads();
    const int w = tid >> 6;
    const int wr0 = (w & 3) * 16;
    const int ch = w >> 2;            // column half
    const int cl = lane & 15, kg = lane >> 4;
    float g2s[16];   // ct gate for this wave's 4 col-tiles (fully unrolled -> registers)

    {   // P2: A = A_I + sigmoid(S@Wop+bop)*(AF@Wa);  g2 = sigmoid(S@ctWg+ctbg)
        #pragma unroll
        for (int nt = 0; nt < 4; ++nt) {
            f32x4 aA = {0.f,0.f,0.f,0.f}, aO = {0.f,0.f,0.f,0.f}, aG = {0.f,0.f,0.f,0.f};
            const int n0 = ch * 64 + nt * 16;
            #pragma unroll
            for (int kk = 0; kk < 4; ++kk) {
                short8 af = AFRAG(sAF, 136, wr0, kk);
                short8 sf = AFRAG(sS, 136, wr0, kk);
                short8 bA = WFRAG(Wat, 128, n0, kk);
                short8 bO = WFRAG(Wopt, 128, n0, kk);
                short8 bG = WFRAG(ctWgt, 128, n0, kk);
                MFMA(aA, af, bA);
                MFMA(aO, sf, bO);
                MFMA(aG, sf, bG);
            }
            const int col = n0 + cl;
            float bopc = bop[col], ctc = ctbg[col];
            #pragma unroll
            for (int i = 0; i < 4; ++i) {
                int r = wr0 + kg * 4 + i;
                float Aval = sA[r * 132 + col] + sigmoidf_(aO[i] + bopc) * aA[i];
                sA[r * 132 + col] = Aval;
                g2s[nt * 4 + i] = sigmoidf_(aG[i] + ctc);
            }
        }
    }
    __syncthreads();
    {   // P3: LN stats of A rows
        const int row = tid >> 3, seg = tid & 7;
        float m = 0.f, q = 0.f;
        #pragma unroll
        for (int u = 0; u < 4; ++u) {
            float4 v = *(const float4*)&sA[row * 132 + seg * 16 + u * 4];
            m += v.x + v.y + v.z + v.w;
            q = fmaf(v.x, v.x, q); q = fmaf(v.y, v.y, q);
            q = fmaf(v.z, v.z, q); q = fmaf(v.w, v.w, q);
        }
        m += __shfl_xor(m, 1); m += __shfl_xor(m, 2); m += __shfl_xor(m, 4);
        q += __shfl_xor(q, 1); q += __shfl_xor(q, 2); q += __shfl_xor(q, 4);
        float mean = m * (1.f / 128.f);
        float rstd = rsqrtf(q * (1.f / 128.f) - mean * mean + 1e-5f);
        if ((tid & 7) == 0) { sMean[row] = mean; sRstd[row] = rstd; }
    }
    __syncthreads();
    {   // P4: an2 = sigmoid(sn@Wg2+bg2)*LN(A) + sn@Ws2  (writes sAn2 = old sAF)
        #pragma unroll
        for (int nt = 0; nt < 4; ++nt) {
            f32x4 ag = {0.f,0.f,0.f,0.f}, as = {0.f,0.f,0.f,0.f};
            const int n0 = ch * 64 + nt * 16;
            #pragma unroll
            for (int kk = 0; kk < 4; ++kk) {
                short8 a = AFRAG(sSn, 136, wr0, kk);
                short8 bg = WFRAG(Wg2t, 128, n0, kk);
                short8 bs = WFRAG(Ws2t, 128, n0, kk);
                MFMA(ag, a, bg);
                MFMA(as, a, bs);
            }
            const int col = n0 + cl;
            float bg2c = bg2[col];
            #pragma unroll
            for (int i = 0; i < 4; ++i) {
                int r = wr0 + kg * 4 + i;
                float lnA = (sA[r * 132 + col] - sMean[r]) * sRstd[r];
                sAn2[r * 136 + col] = f2bf(sigmoidf_(ag[i] + bg2c) * lnA + as[i]);
            }
        }
    }
    __syncthreads();
    {   // P5: b = silu(an2@Wsw) * (an2@Wlin)   (writes sB over sS/sSn region)
        #pragma unroll
        for (int nt = 0; nt < 8; ++nt) {
            f32x4 aw = {0.f,0.f,0.f,0.f}, al = {0.f,0.f,0.f,0.f};
            const int n0 = ch * 128 + nt * 16;
            #pragma unroll
            for (int kk = 0; kk < 4; ++kk) {
                short8 a = AFRAG(sAn2, 136, wr0, kk);
                short8 bw = WFRAG(Wswt, 128, n0, kk);
                short8 bl = WFRAG(Wlint, 128, n0, kk);
                MFMA(aw, a, bw);
                MFMA(al, a, bl);
            }
            const int col2 = n0 + cl;
            #pragma unroll
            for (int i = 0; i < 4; ++i) {
                int r = wr0 + kg * 4 + i;
                float x = aw[i];
                float bb = (x / (1.f + expf(-x))) * al[i];
                sB[r * 264 + col2] = f2bf(bb);
            }
        }
    }
    __syncthreads();
    {   // P6: out = A + g2 * (b @ Wout2)
        #pragma unroll
        for (int nt = 0; nt < 4; ++nt) {
            f32x4 acc = {0.f,0.f,0.f,0.f};
            const int n0 = ch * 64 + nt * 16;
            #pragma unroll
            for (int kk = 0; kk < 8; ++kk) {
                short8 a = AFRAG(sB, 264, wr0, kk);
                short8 b = WFRAG(Wout2t, 256, n0, kk);
                MFMA(acc, a, b);
            }
            const int col = n0 + cl;
            #pragma unroll
            for (int i = 0; i < 4; ++i) {
                int r = wr0 + kg * 4 + i;
                long t = t0 + r;
                Out[t * 128 + col] = sA[r * 132 + col] + g2s[nt * 4 + i] * acc[i];
            }
        }
    }
}

// ---------------------------------------------------------------------------
extern "C" void kernel_launch(void* const* d_in, const int* in_sizes, int n_in,
                              void* d_out, int out_size, void* d_ws, size_t ws_size,
                              hipStream_t stream)
{
    const float* A_I  = (const float*)d_in[0];
    const float* S_I  = (const float*)d_in[1];
    const float* Z    = (const float*)d_in[2];
    const float* maskK = (const float*)d_in[6];
    const float* a1Wg = (const float*)d_in[7];
    const float* a1bg = (const float*)d_in[8];
    const float* a1Ws = (const float*)d_in[9];
    const float* Wq   = (const float*)d_in[10];
    const float* bq   = (const float*)d_in[11];
    const float* Wk   = (const float*)d_in[12];
    const float* Wv   = (const float*)d_in[13];
    const float* ln0g = (const float*)d_in[14];
    const float* ln0b = (const float*)d_in[15];
    const float* Wb   = (const float*)d_in[16];
    const float* Wga  = (const float*)d_in[17];
    const float* Wa   = (const float*)d_in[18];
    const float* Wop  = (const float*)d_in[19];
    const float* bop  = (const float*)d_in[20];
    const float* a2Wg = (const float*)d_in[21];
    const float* a2bg = (const float*)d_in[22];
    const float* a2Ws = (const float*)d_in[23];
    const float* Wsw  = (const float*)d_in[24];
    const float* Wlin = (const float*)d_in[25];
    const float* ctWg = (const float*)d_in[26];
    const float* ctbg = (const float*)d_in[27];
    const float* Wout2 = (const float*)d_in[28];
    float* out = (float*)d_out;

    const size_t NTC = (size_t)DL * 128;   // 2,097,152 elems per (D,L,C) tensor
    short* Qb = (short*)d_ws;
    short* Kb = Qb + NTC;
    short* Vb = Kb + NTC;
    short* Gb = Vb + NTC;
    short* BBt = Gb + NTC;                 // [64][4][128][32] bf16 = 2 MB
    short* wbt = BBt + (size_t)NQB * 4 * 128 * 32;
    short* AFb = Qb;   // attention output aliases Qb (block-local RAW, barrier-separated)

    short* Wg1t = wbt + 0 * 16384;
    short* Ws1t = wbt + 1 * 16384;
    short* Wqt  = wbt + 2 * 16384;
    short* Wkt  = wbt + 3 * 16384;
    short* Wvt  = wbt + 4 * 16384;
    short* Wgat = wbt + 5 * 16384;
    short* Wat  = wbt + 6 * 16384;
    short* Wopt = wbt + 7 * 16384;
    short* ctWgt = wbt + 8 * 16384;
    short* Wg2t = wbt + 9 * 16384;
    short* Ws2t = wbt + 10 * 16384;
    short* Wswt = wbt + 180224;
    short* Wlint = wbt + 212992;
    short* Wout2t = wbt + 245760;

    k_prep<<<273, 256, 0, stream>>>(a1Wg, a1Ws, Wq, Wk, Wv, Wga, Wa, Wop, ctWg,
                                    a2Wg, a2Ws, Wsw, Wlin, Wout2,
                                    Z, ln0g, ln0b, Wb, wbt, BBt);
    k_adaln_qkvg<<<DL / 64, 512, 0, stream>>>(A_I, S_I, Wg1t, Ws1t, Wqt, Wkt, Wvt, Wgat,
                                              a1bg, bq, Qb, Kb, Vb, Gb);
    k_attn<<<dim3(NQB, 8), 256, 0, stream>>>(Qb, Kb, Vb, Gb, BBt, maskK, AFb);
    k_postf<<<DL / 64, 512, 0, stream>>>(AFb, S_I, A_I, Wat, Wopt, ctWgt, Wg2t, Ws2t,
                                         Wswt, Wlint, Wout2t, bop, ctbg, a2bg, out);
}

// Round 6
// 76.002 us; speedup vs baseline: 3.8299x; 1.4040x over previous
//
#include <hip/hip_runtime.h>

// Problem constants
#define DL 16384   // D*L tokens
#define LL 2048
#define NQB 64     // NQ
#define QBS 32     // QB
#define KBS 128    // KB

typedef __attribute__((ext_vector_type(8))) short short8;
typedef __attribute__((ext_vector_type(4))) short short4v;
typedef __attribute__((ext_vector_type(4))) float f32x4;

__device__ __forceinline__ float sigmoidf_(float x) { return 1.f / (1.f + expf(-x)); }

__device__ __forceinline__ short f2bf(float f) {
    union { float f; unsigned u; } v; v.f = f;
    unsigned r = (v.u + 0x7FFFu + ((v.u >> 16) & 1u)) >> 16;
    return (short)r;
}
__device__ __forceinline__ float bf2f(short h) {
    union { unsigned u; float f; } v; v.u = ((unsigned)(unsigned short)h) << 16;
    return v.f;
}

// fragment helpers (cl = lane&15, kg = lane>>4 must be in scope)
#define AFRAG(buf, stride, r0, kk) (*(const short8*)&(buf)[(size_t)((r0) + cl) * (stride) + (kk) * 32 + kg * 8])
#define WFRAG(Wt, K, n0, kk) (*(const short8*)((Wt) + (size_t)((n0) + cl) * (K) + (kk) * 32 + kg * 8))
#define MFMA(acc, a, b) acc = __builtin_amdgcn_mfma_f32_16x16x32_bf16(a, b, acc, 0, 0, 0)

// ---------------------------------------------------------------------------
// Kernel 0: fused prep.
//   blocks 0..16  : weight transpose to bf16 [N][K] via LDS tile
//   blocks 17..528: pair-bias  BBt[n][h][j][i] bf16  (4 query rows per block)
// ---------------------------------------------------------------------------
__global__ __launch_bounds__(256) void k_prep(
    const float* __restrict__ W0, const float* __restrict__ W1, const float* __restrict__ W2,
    const float* __restrict__ W3, const float* __restrict__ W4, const float* __restrict__ W5,
    const float* __restrict__ W6, const float* __restrict__ W7, const float* __restrict__ W8,
    const float* __restrict__ W9, const float* __restrict__ W10,
    const float* __restrict__ Wsw, const float* __restrict__ Wlin, const float* __restrict__ Wout2,
    const float* __restrict__ Z, const float* __restrict__ g16, const float* __restrict__ b16,
    const float* __restrict__ Wb,
    short* __restrict__ wout, short* __restrict__ BBt)
{
    __shared__ float sW[128 * 128];          // 64 KB (weight-transpose path)
    __shared__ float sWb[64], sg[16], sb[16];
    __shared__ short sT[4 * 4 * 128];        // bias path staging [h][il][j]
    const int b = blockIdx.x;
    const int tid = threadIdx.x;

    if (b < 17) {
        const float* srcs[14] = {W0,W1,W2,W3,W4,W5,W6,W7,W8,W9,W10,Wsw,Wlin,Wout2};
        const int sel[17]  = {0,1,2,3,4,5,6,7,8,9,10,11,11,12,12,13,13};
        const int soff[17] = {0,0,0,0,0,0,0,0,0,0,0, 0,128, 0,128, 0,16384};
        const int sN[17]   = {128,128,128,128,128,128,128,128,128,128,128, 256,256,256,256, 128,128};
        const int doff[17] = {0,16384,32768,49152,65536,81920,98304,114688,131072,147456,163840,
                              180224,196608, 212992,229376, 245760,245888};
        const int dK[17]   = {128,128,128,128,128,128,128,128,128,128,128, 128,128,128,128, 256,256};
        const float* src = srcs[sel[b]] + soff[b];
        const int srcN = sN[b];
        short* dst = wout + doff[b];
        const int dstK = dK[b];
        {   // coalesced load of 128x128 f32 tile
            const int r = tid >> 1, ch = (tid & 1) * 64;
            #pragma unroll
            for (int u = 0; u < 16; ++u) {
                float4 v = *(const float4*)(src + (size_t)r * srcN + ch + u * 4);
                *(float4*)&sW[r * 128 + ch + u * 4] = v;
            }
        }
        __syncthreads();
        {   // coalesced transposed bf16 write
            const int o = tid >> 1, kh = (tid & 1) * 64;
            #pragma unroll
            for (int u8 = 0; u8 < 8; ++u8) {
                short8 pk;
                #pragma unroll
                for (int e = 0; e < 8; ++e)
                    pk[e] = f2bf(sW[(kh + u8 * 8 + e) * 128 + o]);
                *(short8*)(dst + (size_t)o * dstK + kh + u8 * 8) = pk;
            }
        }
    } else {
        const int bb = b - 17;           // 0..511
        const int n = bb >> 3;           // 0..63
        const int io = (bb & 7) * 4;     // 4-row slice
        if (tid < 64) sWb[tid] = Wb[tid];
        if (tid < 16) { sg[tid] = g16[tid]; sb[tid] = b16[tid]; }
        __syncthreads();
        #pragma unroll
        for (int p = 0; p < 2; ++p) {
            int pair = tid + 256 * p;        // 4*128 pairs
            int il = pair >> 7, j = pair & 127;
            int i = io + il;
            int kr = n * 32 - 48 + j;
            int kc = min(max(kr, 0), LL - 1);
            const float4* z4 = (const float4*)(Z + ((long)(n * 32 + i) * LL + kc) * 16);
            float zv[16];
            #pragma unroll
            for (int w = 0; w < 4; ++w) {
                float4 v = z4[w];
                zv[w * 4 + 0] = v.x; zv[w * 4 + 1] = v.y; zv[w * 4 + 2] = v.z; zv[w * 4 + 3] = v.w;
            }
            float sm = 0.f, sq = 0.f;
            #pragma unroll
            for (int cp = 0; cp < 16; ++cp) { sm += zv[cp]; sq = fmaf(zv[cp], zv[cp], sq); }
            float m = sm * (1.f / 16.f);
            float rs = rsqrtf(sq * (1.f / 16.f) - m * m + 1e-5f);
            float b0 = 0.f, b1 = 0.f, b2 = 0.f, b3 = 0.f;
            #pragma unroll
            for (int cp = 0; cp < 16; ++cp) {
                float zn = (zv[cp] - m) * rs * sg[cp] + sb[cp];
                b0 = fmaf(zn, sWb[cp * 4 + 0], b0);
                b1 = fmaf(zn, sWb[cp * 4 + 1], b1);
                b2 = fmaf(zn, sWb[cp * 4 + 2], b2);
                b3 = fmaf(zn, sWb[cp * 4 + 3], b3);
            }
            sT[(0 * 4 + il) * 128 + j] = f2bf(b0);
            sT[(1 * 4 + il) * 128 + j] = f2bf(b1);
            sT[(2 * 4 + il) * 128 + j] = f2bf(b2);
            sT[(3 * 4 + il) * 128 + j] = f2bf(b3);
        }
        __syncthreads();
        #pragma unroll
        for (int rr = 0; rr < 2; ++rr) {
            int cid = tid + rr * 256;    // 0..511 = h*128 + j
            int hh = cid >> 7, j = cid & 127;
            short4v pk;
            #pragma unroll
            for (int e = 0; e < 4; ++e) pk[e] = sT[(hh * 4 + e) * 128 + j];
            *(short4v*)(BBt + (((size_t)n * 4 + hh) * 128 + j) * 32 + io) = pk;
        }
    }
}

// ---------------------------------------------------------------------------
// Kernel 1: adaLN1 + QKV+G projections via MFMA.
// 32 tokens / block, 512 threads (8 waves): wave w owns col-tile n0=w*16,
// loops the 2 row-tiles; W fragments loaded once per wave into VGPRs.
// ---------------------------------------------------------------------------
__global__ __launch_bounds__(512) void k_adaln_qkvg(
    const float* __restrict__ A_I, const float* __restrict__ S_I,
    const short* __restrict__ Wg1t, const short* __restrict__ Ws1t,
    const short* __restrict__ Wqt, const short* __restrict__ Wkt,
    const short* __restrict__ Wvt, const short* __restrict__ Wgat,
    const float* __restrict__ bg1, const float* __restrict__ bq,
    short* __restrict__ Qo, short* __restrict__ Ko, short* __restrict__ Vo, short* __restrict__ Go)
{
    __shared__ short sAr[32 * 136];   // raw A bf16
    __shared__ short sSn[32 * 136];   // LN(S) bf16
    __shared__ short sAn[32 * 136];   // An bf16
    __shared__ float sMean[32], sRstd[32];
    const int tid = threadIdx.x;
    const int lane = tid & 63;
    const long t0 = (long)blockIdx.x * 32;

    {   // P0: load A,S (8 f32/thread); LN stats over 16-lane groups; stage bf16
        const int row = tid >> 4, seg = tid & 15;
        const float* ap = A_I + (t0 + row) * 128 + seg * 8;
        const float* sp = S_I + (t0 + row) * 128 + seg * 8;
        float av[8], sv[8];
        #pragma unroll
        for (int u = 0; u < 2; ++u) {
            float4 a4 = ((const float4*)ap)[u];
            float4 s4 = ((const float4*)sp)[u];
            av[4*u] = a4.x; av[4*u+1] = a4.y; av[4*u+2] = a4.z; av[4*u+3] = a4.w;
            sv[4*u] = s4.x; sv[4*u+1] = s4.y; sv[4*u+2] = s4.z; sv[4*u+3] = s4.w;
        }
        float am = 0.f, aq = 0.f, sm = 0.f, sq = 0.f;
        #pragma unroll
        for (int u = 0; u < 8; ++u) {
            am += av[u]; aq = fmaf(av[u], av[u], aq);
            sm += sv[u]; sq = fmaf(sv[u], sv[u], sq);
        }
        am += __shfl_xor(am, 1); am += __shfl_xor(am, 2); am += __shfl_xor(am, 4); am += __shfl_xor(am, 8);
        aq += __shfl_xor(aq, 1); aq += __shfl_xor(aq, 2); aq += __shfl_xor(aq, 4); aq += __shfl_xor(aq, 8);
        sm += __shfl_xor(sm, 1); sm += __shfl_xor(sm, 2); sm += __shfl_xor(sm, 4); sm += __shfl_xor(sm, 8);
        sq += __shfl_xor(sq, 1); sq += __shfl_xor(sq, 2); sq += __shfl_xor(sq, 4); sq += __shfl_xor(sq, 8);
        float amean = am * (1.f / 128.f);
        float arstd = rsqrtf(aq * (1.f / 128.f) - amean * amean + 1e-5f);
        float smean = sm * (1.f / 128.f);
        float srstd = rsqrtf(sq * (1.f / 128.f) - smean * smean + 1e-5f);
        if ((tid & 15) == 0) { sMean[row] = amean; sRstd[row] = arstd; }
        short8 pa, ps;
        #pragma unroll
        for (int e = 0; e < 8; ++e) {
            pa[e] = f2bf(av[e]);
            ps[e] = f2bf((sv[e] - smean) * srstd);
        }
        *(short8*)&sAr[row * 136 + seg * 8] = pa;
        *(short8*)&sSn[row * 136 + seg * 8] = ps;
    }
    __syncthreads();
    const int w = tid >> 6;
    const int n0 = w * 16;            // this wave's 16 output cols
    const int cl = lane & 15, kg = lane >> 4;
    {   // P1: An = sigmoid(sn@Wg1+bg1)*an + sn@Ws1
        short8 wg[4], wsf[4];
        #pragma unroll
        for (int kk = 0; kk < 4; ++kk) {
            wg[kk]  = WFRAG(Wg1t, 128, n0, kk);
            wsf[kk] = WFRAG(Ws1t, 128, n0, kk);
        }
        #pragma unroll
        for (int mt = 0; mt < 2; ++mt) {
            f32x4 ag = {0.f, 0.f, 0.f, 0.f}, as = {0.f, 0.f, 0.f, 0.f};
            #pragma unroll
            for (int kk = 0; kk < 4; ++kk) {
                short8 a = AFRAG(sSn, 136, mt * 16, kk);
                MFMA(ag, a, wg[kk]);
                MFMA(as, a, wsf[kk]);
            }
            const int col = n0 + cl;
            float bgc = bg1[col];
            #pragma unroll
            for (int i = 0; i < 4; ++i) {
                int r = mt * 16 + kg * 4 + i;
                float an = (bf2f(sAr[r * 136 + col]) - sMean[r]) * sRstd[r];
                float An = sigmoidf_(ag[i] + bgc) * an + as[i];
                sAn[r * 136 + col] = f2bf(An);
            }
        }
    }
    __syncthreads();
    {   // P2: Q,K,V,G = An @ {Wq,Wk,Wv,Wga}; A-frags cached, W loaded per matrix
        const float SCL = 0.17677669529663687f;  // 1/sqrt(32)
        short8 af[2][4];
        #pragma unroll
        for (int mt = 0; mt < 2; ++mt)
            #pragma unroll
            for (int kk = 0; kk < 4; ++kk)
                af[mt][kk] = AFRAG(sAn, 136, mt * 16, kk);
        #pragma unroll
        for (int m = 0; m < 4; ++m) {
            const short* Wt = (m == 0) ? Wqt : (m == 1) ? Wkt : (m == 2) ? Wvt : Wgat;
            short8 wf[4];
            #pragma unroll
            for (int kk = 0; kk < 4; ++kk) wf[kk] = WFRAG(Wt, 128, n0, kk);
            #pragma unroll
            for (int mt = 0; mt < 2; ++mt) {
                f32x4 acc = {0.f, 0.f, 0.f, 0.f};
                #pragma unroll
                for (int kk = 0; kk < 4; ++kk) MFMA(acc, af[mt][kk], wf[kk]);
                const int col = n0 + cl;
                #pragma unroll
                for (int i = 0; i < 4; ++i) {
                    long t = t0 + mt * 16 + kg * 4 + i;
                    float v = acc[i];
                    if (m == 0)      Qo[t * 128 + col] = f2bf((v + bq[col]) * SCL);
                    else if (m == 1) Ko[t * 128 + col] = f2bf(v);
                    else if (m == 2) Vo[t * 128 + col] = f2bf(v);
                    else             Go[t * 128 + col] = f2bf(sigmoidf_(v));
                }
            }
        }
    }
}

// ---------------------------------------------------------------------------
// Kernel 3: windowed attention, block = (n,d), wave = head.
// Q/K fragments straight from global; scores in registers; V^T + P in LDS.
// ---------------------------------------------------------------------------
__global__ __launch_bounds__(256) void k_attn(
    const short* __restrict__ Qg, const short* __restrict__ Kg, const short* __restrict__ Vg,
    const short* __restrict__ Gg, const short* __restrict__ BBt, const float* __restrict__ maskK,
    short* __restrict__ AFo)
{
    __shared__ short vts[4 * 32 * 136];   // per-head V^T [c][key]
    __shared__ short Pl [4 * 32 * 136];   // per-head P [q][key]
    const int n = blockIdx.x, d = blockIdx.y;
    const int tid = threadIdx.x;
    const int lane = tid & 63;
    const int h = tid >> 6;
    const long tb = (long)d * LL;
    const int kbase = n * 32 - 48;
    short* vtsH = vts + h * 4352;
    short* PH   = Pl  + h * 4352;
    const int cl = lane & 15, kg = lane >> 4;

    {   // V transpose: lane handles keys 2*lane, 2*lane+1, channels 0..31 of head h
        const int j0 = lane * 2;
        int kc0 = min(max(kbase + j0, 0), LL - 1);
        int kc1 = min(max(kbase + j0 + 1, 0), LL - 1);
        const short8* p0 = (const short8*)(Vg + (tb + kc0) * 128 + h * 32);
        const short8* p1 = (const short8*)(Vg + (tb + kc1) * 128 + h * 32);
        short8 ev[4] = {p0[0], p0[1], p0[2], p0[3]};
        short8 ov[4] = {p1[0], p1[1], p1[2], p1[3]};
        #pragma unroll
        for (int g = 0; g < 4; ++g)
            #pragma unroll
            for (int e = 0; e < 8; ++e)
                *(unsigned*)&vtsH[(g * 8 + e) * 136 + j0] =
                    (unsigned)(unsigned short)ev[g][e] | ((unsigned)(unsigned short)ov[g][e] << 16);
    }
    __syncthreads();

    float sc[2][8][4];
    {   // QK^T straight from global + bias + mask
        short8 qf[2];
        #pragma unroll
        for (int mt = 0; mt < 2; ++mt)
            qf[mt] = *(const short8*)(Qg + (tb + n * 32 + mt * 16 + cl) * 128 + h * 32 + kg * 8);
        #pragma unroll
        for (int nt = 0; nt < 8; ++nt) {
            const int key = nt * 16 + cl;
            int kc = min(max(kbase + key, 0), LL - 1);
            short8 kf = *(const short8*)(Kg + (tb + kc) * 128 + h * 32 + kg * 8);
            float mk = maskK[n * 128 + key] * 1e9f;
            #pragma unroll
            for (int mt = 0; mt < 2; ++mt) {
                f32x4 s = {0.f, 0.f, 0.f, 0.f};
                MFMA(s, qf[mt], kf);
                short4v bfr = *(const short4v*)(BBt + (((size_t)n * 4 + h) * 128 + key) * 32 + mt * 16 + kg * 4);
                #pragma unroll
                for (int i = 0; i < 4; ++i)
                    sc[mt][nt][i] = s[i] + bf2f(bfr[i]) - mk;
            }
        }
    }
    {   // in-register softmax per q-row (16-lane cl-group holds the 128 keys)
        #pragma unroll
        for (int mt = 0; mt < 2; ++mt) {
            #pragma unroll
            for (int i = 0; i < 4; ++i) {
                float mx = sc[mt][0][i];
                #pragma unroll
                for (int nt = 1; nt < 8; ++nt) mx = fmaxf(mx, sc[mt][nt][i]);
                mx = fmaxf(mx, __shfl_xor(mx, 1));
                mx = fmaxf(mx, __shfl_xor(mx, 2));
                mx = fmaxf(mx, __shfl_xor(mx, 4));
                mx = fmaxf(mx, __shfl_xor(mx, 8));
                float sm = 0.f;
                #pragma unroll
                for (int nt = 0; nt < 8; ++nt) {
                    float p = __expf(sc[mt][nt][i] - mx);
                    sc[mt][nt][i] = p; sm += p;
                }
                sm += __shfl_xor(sm, 1);
                sm += __shfl_xor(sm, 2);
                sm += __shfl_xor(sm, 4);
                sm += __shfl_xor(sm, 8);
                float inv = 1.f / sm;
                const int q = mt * 16 + kg * 4 + i;
                #pragma unroll
                for (int nt = 0; nt < 8; ++nt)
                    PH[q * 136 + nt * 16 + cl] = f2bf(sc[mt][nt][i] * inv);
            }
        }
    }
    __syncthreads();
    {   // PV + G-gate + store
        #pragma unroll
        for (int mt = 0; mt < 2; ++mt) {
            #pragma unroll
            for (int ct = 0; ct < 2; ++ct) {
                f32x4 acc = {0.f, 0.f, 0.f, 0.f};
                #pragma unroll
                for (int kk = 0; kk < 4; ++kk) {
                    short8 a = *(const short8*)&PH[(mt * 16 + cl) * 136 + kk * 32 + kg * 8];
                    short8 b = *(const short8*)&vtsH[(ct * 16 + cl) * 136 + kk * 32 + kg * 8];
                    MFMA(acc, a, b);
                }
                const int col = h * 32 + ct * 16 + cl;
                #pragma unroll
                for (int i = 0; i < 4; ++i) {
                    long t = tb + n * 32 + mt * 16 + kg * 4 + i;
                    float g = bf2f(Gg[t * 128 + col]);
                    AFo[t * 128 + col] = f2bf(g * acc[i]);
                }
            }
        }
    }
}

// ---------------------------------------------------------------------------
// Kernel 4: fused post: af@Wa gate residual + adaLN2 + SwiGLU + ct-gate.
// 32 tokens / block, 512 threads (8 waves): wave w owns col-tile n0=w*16,
// loops the 2 row-tiles; W fragments in VGPRs.
// ---------------------------------------------------------------------------
__global__ __launch_bounds__(512) void k_postf(
    const short* __restrict__ AF, const float* __restrict__ S_I, const float* __restrict__ A_I,
    const short* __restrict__ Wat, const short* __restrict__ Wopt, const short* __restrict__ ctWgt,
    const short* __restrict__ Wg2t, const short* __restrict__ Ws2t,
    const short* __restrict__ Wswt, const short* __restrict__ Wlint, const short* __restrict__ Wout2t,
    const float* __restrict__ bop, const float* __restrict__ ctbg, const float* __restrict__ bg2,
    float* __restrict__ Out)
{
    __shared__ __align__(16) char smem[43264];
    short* sAF  = (short*)smem;              // [32][136] bf16 AF       -> reused as sAn2
    short* sS   = (short*)(smem + 8704);     // [32][136] bf16 raw S    -> reused by sB
    short* sSn  = (short*)(smem + 17408);    // [32][136] bf16 LN(S)    (partly reused by sB)
    float* sA   = (float*)(smem + 26112);    // [32][132] f32: raw A_I in P0, final A after P2
    float* sMean = (float*)(smem + 43008);   // [32]
    float* sRstd = (float*)(smem + 43136);   // [32]
    short* sAn2 = sAF;                       // [32][136] bf16 an2
    short* sB   = (short*)(smem + 8704);     // [32][264] bf16 b (16896 B, ends 25600 < 26112)

    const int tid = threadIdx.x;
    const int lane = tid & 63;
    const long t0 = (long)blockIdx.x * 32;

    {   // P0: copy AF (bf16); load A_I -> sA f32; load S -> raw bf16 + LN bf16
        const int row = tid >> 4, seg = tid & 15;
        *(short8*)&sAF[row * 136 + seg * 8] =
            *(const short8*)(AF + (t0 + row) * 128 + seg * 8);
        const float* apI = A_I + (t0 + row) * 128 + seg * 8;
        #pragma unroll
        for (int u = 0; u < 2; ++u)
            *(float4*)&sA[row * 132 + seg * 8 + u * 4] = ((const float4*)apI)[u];
        const float* sp = S_I + (t0 + row) * 128 + seg * 8;
        float sv[8];
        #pragma unroll
        for (int u = 0; u < 2; ++u) {
            float4 s4 = ((const float4*)sp)[u];
            sv[4*u] = s4.x; sv[4*u+1] = s4.y; sv[4*u+2] = s4.z; sv[4*u+3] = s4.w;
        }
        float sm = 0.f, sq = 0.f;
        #pragma unroll
        for (int u = 0; u < 8; ++u) { sm += sv[u]; sq = fmaf(sv[u], sv[u], sq); }
        sm += __shfl_xor(sm, 1); sm += __shfl_xor(sm, 2); sm += __shfl_xor(sm, 4); sm += __shfl_xor(sm, 8);
        sq += __shfl_xor(sq, 1); sq += __shfl_xor(sq, 2); sq += __shfl_xor(sq, 4); sq += __shfl_xor(sq, 8);
        float smean = sm * (1.f / 128.f);
        float srstd = rsqrtf(sq * (1.f / 128.f) - smean * smean + 1e-5f);
        short8 pr, pn;
        #pragma unroll
        for (int e = 0; e < 8; ++e) {
            float s = sv[e];
            pr[e] = f2bf(s);
            pn[e] = f2bf((s - smean) * srstd);
        }
        *(short8*)&sS [row * 136 + seg * 8] = pr;
        *(short8*)&sSn[row * 136 + seg * 8] = pn;
    }
    __syncthreads();
    const int w = tid >> 6;
    const int n0 = w * 16;            // this wave's 16 output cols
    const int cl = lane & 15, kg = lane >> 4;
    float g2s[8];   // ct gate for this wave's col-tile (static indexing -> registers)

    {   // P2: A = A_I + sigmoid(S@Wop+bop)*(AF@Wa);  g2 = sigmoid(S@ctWg+ctbg)
        short8 wA[4], wO[4], wG[4];
        #pragma unroll
        for (int kk = 0; kk < 4; ++kk) {
            wA[kk] = WFRAG(Wat, 128, n0, kk);
            wO[kk] = WFRAG(Wopt, 128, n0, kk);
            wG[kk] = WFRAG(ctWgt, 128, n0, kk);
        }
        #pragma unroll
        for (int mt = 0; mt < 2; ++mt) {
            f32x4 aA = {0.f,0.f,0.f,0.f}, aO = {0.f,0.f,0.f,0.f}, aG = {0.f,0.f,0.f,0.f};
            #pragma unroll
            for (int kk = 0; kk < 4; ++kk) {
                short8 af = AFRAG(sAF, 136, mt * 16, kk);
                short8 sf = AFRAG(sS, 136, mt * 16, kk);
                MFMA(aA, af, wA[kk]);
                MFMA(aO, sf, wO[kk]);
                MFMA(aG, sf, wG[kk]);
            }
            const int col = n0 + cl;
            float bopc = bop[col], ctc = ctbg[col];
            #pragma unroll
            for (int i = 0; i < 4; ++i) {
                int r = mt * 16 + kg * 4 + i;
                float Aval = sA[r * 132 + col] + sigmoidf_(aO[i] + bopc) * aA[i];
                sA[r * 132 + col] = Aval;
                g2s[mt * 4 + i] = sigmoidf_(aG[i] + ctc);
            }
        }
    }
    __syncthreads();
    {   // P3: LN stats of A rows
        const int row = tid >> 4, seg = tid & 15;
        float m = 0.f, q = 0.f;
        #pragma unroll
        for (int u = 0; u < 2; ++u) {
            float4 v = *(const float4*)&sA[row * 132 + seg * 8 + u * 4];
            m += v.x + v.y + v.z + v.w;
            q = fmaf(v.x, v.x, q); q = fmaf(v.y, v.y, q);
            q = fmaf(v.z, v.z, q); q = fmaf(v.w, v.w, q);
        }
        m += __shfl_xor(m, 1); m += __shfl_xor(m, 2); m += __shfl_xor(m, 4); m += __shfl_xor(m, 8);
        q += __shfl_xor(q, 1); q += __shfl_xor(q, 2); q += __shfl_xor(q, 4); q += __shfl_xor(q, 8);
        float mean = m * (1.f / 128.f);
        float rstd = rsqrtf(q * (1.f / 128.f) - mean * mean + 1e-5f);
        if ((tid & 15) == 0) { sMean[row] = mean; sRstd[row] = rstd; }
    }
    __syncthreads();
    {   // P4: an2 = sigmoid(sn@Wg2+bg2)*LN(A) + sn@Ws2  (writes sAn2 = old sAF)
        short8 wg2[4], ws2[4];
        #pragma unroll
        for (int kk = 0; kk < 4; ++kk) {
            wg2[kk] = WFRAG(Wg2t, 128, n0, kk);
            ws2[kk] = WFRAG(Ws2t, 128, n0, kk);
        }
        #pragma unroll
        for (int mt = 0; mt < 2; ++mt) {
            f32x4 ag = {0.f,0.f,0.f,0.f}, as = {0.f,0.f,0.f,0.f};
            #pragma unroll
            for (int kk = 0; kk < 4; ++kk) {
                short8 a = AFRAG(sSn, 136, mt * 16, kk);
                MFMA(ag, a, wg2[kk]);
                MFMA(as, a, ws2[kk]);
            }
            const int col = n0 + cl;
            float bg2c = bg2[col];
            #pragma unroll
            for (int i = 0; i < 4; ++i) {
                int r = mt * 16 + kg * 4 + i;
                float lnA = (sA[r * 132 + col] - sMean[r]) * sRstd[r];
                sAn2[r * 136 + col] = f2bf(sigmoidf_(ag[i] + bg2c) * lnA + as[i]);
            }
        }
    }
    __syncthreads();
    {   // P5: b = silu(an2@Wsw) * (an2@Wlin)  -> sB (over sS/sSn); wave does 2 col-tiles
        short8 a2f[2][4];
        #pragma unroll
        for (int mt = 0; mt < 2; ++mt)
            #pragma unroll
            for (int kk = 0; kk < 4; ++kk)
                a2f[mt][kk] = AFRAG(sAn2, 136, mt * 16, kk);
        #pragma unroll
        for (int j = 0; j < 2; ++j) {
            const int n0b = w * 32 + j * 16;
            short8 ww[4], wl[4];
            #pragma unroll
            for (int kk = 0; kk < 4; ++kk) {
                ww[kk] = WFRAG(Wswt, 128, n0b, kk);
                wl[kk] = WFRAG(Wlint, 128, n0b, kk);
            }
            #pragma unroll
            for (int mt = 0; mt < 2; ++mt) {
                f32x4 aw = {0.f,0.f,0.f,0.f}, al = {0.f,0.f,0.f,0.f};
                #pragma unroll
                for (int kk = 0; kk < 4; ++kk) {
                    MFMA(aw, a2f[mt][kk], ww[kk]);
                    MFMA(al, a2f[mt][kk], wl[kk]);
                }
                const int col2 = n0b + cl;
                #pragma unroll
                for (int i = 0; i < 4; ++i) {
                    int r = mt * 16 + kg * 4 + i;
                    float x = aw[i];
                    float bb = (x / (1.f + expf(-x))) * al[i];
                    sB[r * 264 + col2] = f2bf(bb);
                }
            }
        }
    }
    __syncthreads();
    {   // P6: out = A + g2 * (b @ Wout2)
        short8 wo[8];
        #pragma unroll
        for (int kk = 0; kk < 8; ++kk) wo[kk] = WFRAG(Wout2t, 256, n0, kk);
        #pragma unroll
        for (int mt = 0; mt < 2; ++mt) {
            f32x4 acc = {0.f,0.f,0.f,0.f};
            #pragma unroll
            for (int kk = 0; kk < 8; ++kk) {
                short8 a = AFRAG(sB, 264, mt * 16, kk);
                MFMA(acc, a, wo[kk]);
            }
            const int col = n0 + cl;
            #pragma unroll
            for (int i = 0; i < 4; ++i) {
                int r = mt * 16 + kg * 4 + i;
                long t = t0 + r;
                Out[t * 128 + col] = sA[r * 132 + col] + g2s[mt * 4 + i] * acc[i];
            }
        }
    }
}

// ---------------------------------------------------------------------------
extern "C" void kernel_launch(void* const* d_in, const int* in_sizes, int n_in,
                              void* d_out, int out_size, void* d_ws, size_t ws_size,
                              hipStream_t stream)
{
    const float* A_I  = (const float*)d_in[0];
    const float* S_I  = (const float*)d_in[1];
    const float* Z    = (const float*)d_in[2];
    const float* maskK = (const float*)d_in[6];
    const float* a1Wg = (const float*)d_in[7];
    const float* a1bg = (const float*)d_in[8];
    const float* a1Ws = (const float*)d_in[9];
    const float* Wq   = (const float*)d_in[10];
    const float* bq   = (const float*)d_in[11];
    const float* Wk   = (const float*)d_in[12];
    const float* Wv   = (const float*)d_in[13];
    const float* ln0g = (const float*)d_in[14];
    const float* ln0b = (const float*)d_in[15];
    const float* Wb   = (const float*)d_in[16];
    const float* Wga  = (const float*)d_in[17];
    const float* Wa   = (const float*)d_in[18];
    const float* Wop  = (const float*)d_in[19];
    const float* bop  = (const float*)d_in[20];
    const float* a2Wg = (const float*)d_in[21];
    const float* a2bg = (const float*)d_in[22];
    const float* a2Ws = (const float*)d_in[23];
    const float* Wsw  = (const float*)d_in[24];
    const float* Wlin = (const float*)d_in[25];
    const float* ctWg = (const float*)d_in[26];
    const float* ctbg = (const float*)d_in[27];
    const float* Wout2 = (const float*)d_in[28];
    float* out = (float*)d_out;

    const size_t NTC = (size_t)DL * 128;   // 2,097,152 elems per (D,L,C) tensor
    short* Qb = (short*)d_ws;
    short* Kb = Qb + NTC;
    short* Vb = Kb + NTC;
    short* Gb = Vb + NTC;
    short* BBt = Gb + NTC;                 // [64][4][128][32] bf16 = 2 MB
    short* wbt = BBt + (size_t)NQB * 4 * 128 * 32;
    short* AFb = Qb;   // attention output aliases Qb (block-local RAW, barrier-separated)

    short* Wg1t = wbt + 0 * 16384;
    short* Ws1t = wbt + 1 * 16384;
    short* Wqt  = wbt + 2 * 16384;
    short* Wkt  = wbt + 3 * 16384;
    short* Wvt  = wbt + 4 * 16384;
    short* Wgat = wbt + 5 * 16384;
    short* Wat  = wbt + 6 * 16384;
    short* Wopt = wbt + 7 * 16384;
    short* ctWgt = wbt + 8 * 16384;
    short* Wg2t = wbt + 9 * 16384;
    short* Ws2t = wbt + 10 * 16384;
    short* Wswt = wbt + 180224;
    short* Wlint = wbt + 212992;
    short* Wout2t = wbt + 245760;

    k_prep<<<529, 256, 0, stream>>>(a1Wg, a1Ws, Wq, Wk, Wv, Wga, Wa, Wop, ctWg,
                                    a2Wg, a2Ws, Wsw, Wlin, Wout2,
                                    Z, ln0g, ln0b, Wb, wbt, BBt);
    k_adaln_qkvg<<<DL / 32, 512, 0, stream>>>(A_I, S_I, Wg1t, Ws1t, Wqt, Wkt, Wvt, Wgat,
                                              a1bg, bq, Qb, Kb, Vb, Gb);
    k_attn<<<dim3(NQB, 8), 256, 0, stream>>>(Qb, Kb, Vb, Gb, BBt, maskK, AFb);
    k_postf<<<DL / 32, 512, 0, stream>>>(AFb, S_I, A_I, Wat, Wopt, ctWgt, Wg2t, Ws2t,
                                         Wswt, Wlint, Wout2t, bop, ctbg, a2bg, out);
}